// Round 8
// baseline (368.276 us; speedup 1.0000x reference)
//
#include <hip/hip_runtime.h>
#include <hip/hip_bf16.h>
#include <math.h>

#define T_TOK 16384
#define CC 256
#define PP 16
#define HH 8
#define DD 32
#define LN_EPS 1e-5f

typedef __attribute__((ext_vector_type(8))) short bf16x8_t;
typedef __attribute__((ext_vector_type(4))) float f32x4_t;

__device__ __forceinline__ unsigned short f2bf(float x) {
  __hip_bfloat16 h = __float2bfloat16(x);
  return *reinterpret_cast<unsigned short*>(&h);
}
__device__ __forceinline__ float bf2f(unsigned short u) {
  union { unsigned int i; float f; } v; v.i = ((unsigned int)u) << 16; return v.f;
}
// async global->LDS, 16B per lane; LDS dest must be wave-uniform base + lane*16
__device__ __forceinline__ void gl_lds16(const unsigned short* g, unsigned short* l) {
  __builtin_amdgcn_global_load_lds(
      (const __attribute__((address_space(1))) unsigned int*)g,
      (__attribute__((address_space(3))) unsigned int*)l, 16, 0, 0);
}

// ---------------------------------------------------------------------------
// Prep kernels
// ---------------------------------------------------------------------------
__global__ __launch_bounds__(256) void cvt_bf16_kernel(const float* __restrict__ src,
                                                       unsigned short* __restrict__ dst) {
  int i = (blockIdx.x * 256 + threadIdx.x) * 4;
  float4 v = *(const float4*)&src[i];
  ushort4 o = make_ushort4(f2bf(v.x), f2bf(v.y), f2bf(v.z), f2bf(v.w));
  *(ushort4*)&dst[i] = o;
}

__global__ __launch_bounds__(256) void transpose_cvt_kernel(const float* __restrict__ src,
                                                            unsigned short* __restrict__ dst,
                                                            int K, int N) {
  __shared__ float tile[64][65];
  int k0 = blockIdx.x * 64, n0 = blockIdx.y * 64;
  int tid = threadIdx.x;
#pragma unroll
  for (int i = 0; i < 16; i++) {
    int lin = i * 256 + tid, r = lin >> 6, c = lin & 63;
    tile[r][c] = src[(size_t)(k0 + r) * N + n0 + c];
  }
  __syncthreads();
#pragma unroll
  for (int i = 0; i < 16; i++) {
    int lin = i * 256 + tid, n = lin >> 6, k = lin & 63;
    dst[(size_t)(n0 + n) * K + k0 + k] = f2bf(tile[k][n]);
  }
}

// Mt[(h*256+e)][c] = bf16( sum_d Wq[c][h*32+d] * Wk[e][h*32+d] )
__global__ __launch_bounds__(256) void precM_kernel(const float* __restrict__ Wq,
                                                    const float* __restrict__ Wk,
                                                    unsigned short* __restrict__ Mt) {
  __shared__ float wqS[256][33];
  __shared__ float wkS[128][33];
  const int tid = threadIdx.x;
  const int h = blockIdx.x >> 1, eh = blockIdx.x & 1;
#pragma unroll
  for (int it = 0; it < 32; it++) {
    int lin = it * 256 + tid, r = lin >> 5, d = lin & 31;
    wqS[r][d] = Wq[(size_t)r * CC + h * DD + d];
  }
#pragma unroll
  for (int it = 0; it < 16; it++) {
    int lin = it * 256 + tid, r = lin >> 5, d = lin & 31;
    wkS[r][d] = Wk[(size_t)(eh * 128 + r) * CC + h * DD + d];
  }
  __syncthreads();
  const int w = tid >> 6, l = tid & 63;
  for (int ei = 0; ei < 32; ei++) {
    int e = w * 32 + ei;
    float o[4] = {0.f, 0.f, 0.f, 0.f};
#pragma unroll
    for (int d = 0; d < 32; d++) {
      float kv = wkS[e][d];
      o[0] += kv * wqS[l][d];
      o[1] += kv * wqS[l + 64][d];
      o[2] += kv * wqS[l + 128][d];
      o[3] += kv * wqS[l + 192][d];
    }
    size_t rowb = (size_t)(h * 256 + eh * 128 + e) * CC;
    Mt[rowb + l] = f2bf(o[0]);
    Mt[rowb + l + 64] = f2bf(o[1]);
    Mt[rowb + l + 128] = f2bf(o[2]);
    Mt[rowb + l + 192] = f2bf(o[3]);
  }
}

// WVMt[c][h*256+e] = bf16( sum_d Wv[e][h*32+d] * Wm[h*32+d][c] ); grid = 8 (h)
__global__ __launch_bounds__(256) void precWVM_kernel(const float* __restrict__ Wv,
                                                      const float* __restrict__ Wm,
                                                      unsigned short* __restrict__ WVMt) {
  __shared__ float WvS[256][33];
  __shared__ float WmS[32][257];
  const int h = blockIdx.x;
  const int tid = threadIdx.x;
#pragma unroll
  for (int it = 0; it < 32; it++) {
    int lin = it * 256 + tid, e = lin >> 5, d = lin & 31;
    WvS[e][d] = Wv[(size_t)e * CC + h * DD + d];
  }
#pragma unroll
  for (int it = 0; it < 32; it++) {
    int lin = it * 256 + tid, d = lin >> 8, c = lin & 255;
    WmS[d][c] = Wm[(size_t)(h * DD + d) * CC + c];
  }
  __syncthreads();
  float wm[32];
#pragma unroll
  for (int d = 0; d < 32; d++) wm[d] = WmS[d][tid];
  for (int e = 0; e < 256; e++) {
    float acc = 0.f;
#pragma unroll
    for (int d = 0; d < 32; d++) acc += WvS[e][d] * wm[d];
    WVMt[(size_t)tid * 2048 + h * 256 + e] = f2bf(acc);
  }
}

// ---------------------------------------------------------------------------
// QK GEMM: Out = A[M,256] @ Bt^T, BM=64 BN=256 BK=32, 512 thr.
// 2-phase: STAGE(next) issued before compute(cur); 1 barrier/K-step.
// ---------------------------------------------------------------------------
__global__ __launch_bounds__(512) void qk_gemm_kernel(
    const unsigned short* __restrict__ A, const unsigned short* __restrict__ Bt,
    unsigned short* __restrict__ Out, int K, int strideO) {
  __shared__ __align__(16) unsigned short As[2][64 * 32];
  __shared__ __align__(16) unsigned short Bs[2][256 * 32];
  const int tid = threadIdx.x;
  const int wv = tid >> 6, l = tid & 63;
  const int wr = wv >> 2, wc = wv & 3;
  const int lr = l & 15, lq = l >> 4;
  const int m0 = blockIdx.x * 64;
  const int n0 = blockIdx.y * 256;
  const int nsteps = K >> 5;

  f32x4_t acc[2][4];
#pragma unroll
  for (int m = 0; m < 2; m++)
#pragma unroll
    for (int n = 0; n < 4; n++) acc[m][n] = (f32x4_t){0.f, 0.f, 0.f, 0.f};

  const int rA = tid >> 2, sA = tid & 3, qA = sA ^ ((rA >> 1) & 3);

  // prologue: stage step 0 into buf 0
  if (tid < 256) gl_lds16(&A[(size_t)(m0 + rA) * K + qA * 8], &As[0][tid * 8]);
#pragma unroll
  for (int it = 0; it < 2; it++) {
    int lin = it * 512 + tid, r = lin >> 2, s = lin & 3, q = s ^ ((r >> 1) & 3);
    gl_lds16(&Bt[(size_t)(n0 + r) * K + q * 8], &Bs[0][lin * 8]);
  }
  __syncthreads();

  for (int st = 0; st < nsteps; st++) {
    int cur = st & 1;
    if (st + 1 < nsteps) {   // STAGE next tile into buf^1 (overlaps compute)
      int kn = (st + 1) * 32;
      if (tid < 256) gl_lds16(&A[(size_t)(m0 + rA) * K + kn + qA * 8], &As[cur ^ 1][tid * 8]);
#pragma unroll
      for (int it = 0; it < 2; it++) {
        int lin = it * 512 + tid, r = lin >> 2, s = lin & 3, q = s ^ ((r >> 1) & 3);
        gl_lds16(&Bt[(size_t)(n0 + r) * K + kn + q * 8], &Bs[cur ^ 1][lin * 8]);
      }
    }
    bf16x8_t af[2], bfr[4];
#pragma unroll
    for (int m = 0; m < 2; m++) {
      int r = wr * 32 + m * 16 + lr;
      int s = lq ^ ((r >> 1) & 3);
      af[m] = *(const bf16x8_t*)&As[cur][r * 32 + s * 8];
    }
#pragma unroll
    for (int n = 0; n < 4; n++) {
      int r = wc * 64 + n * 16 + lr;
      int s = lq ^ ((r >> 1) & 3);
      bfr[n] = *(const bf16x8_t*)&Bs[cur][r * 32 + s * 8];
    }
#pragma unroll
    for (int m = 0; m < 2; m++)
#pragma unroll
      for (int n = 0; n < 4; n++)
        acc[m][n] = __builtin_amdgcn_mfma_f32_16x16x32_bf16(af[m], bfr[n], acc[m][n], 0, 0, 0);
    __syncthreads();   // drains vmcnt (next tile ready) + guards buf reuse
  }

#pragma unroll
  for (int m = 0; m < 2; m++)
#pragma unroll
    for (int n = 0; n < 4; n++)
#pragma unroll
      for (int j = 0; j < 4; j++) {
        int rl = wr * 32 + m * 16 + lq * 4 + j;
        int col = n0 + wc * 64 + n * 16 + lr;
        Out[(size_t)(m0 + rl) * strideO + col] = f2bf(acc[m][n][j]);
      }
}

// ---------------------------------------------------------------------------
// attn2: per wave = one token. Unchanged (validated round 6/7).
// ---------------------------------------------------------------------------
__global__ __launch_bounds__(256) void attn2_kernel(const unsigned short* __restrict__ QKc,
                                                    const float* __restrict__ target,
                                                    const float* __restrict__ wts,
                                                    const float* __restrict__ conf,
                                                    unsigned short* __restrict__ TC) {
  __shared__ __align__(16) unsigned short Ts[4][16 * 256];
  __shared__ float awL[4][PP][HH];
  const int tid = threadIdx.x;
  const int w = tid >> 6, l = tid & 63;
  const int t = blockIdx.x * 4 + w;
  const float* trow = target + (size_t)t * PP * CC;
  char* tsb = (char*)&Ts[w][0];

  {
    const int p = l >> 2;
#pragma unroll
    for (int i = 0; i < 8; i++) {
      int s = (l & 3) + i * 4;
      const float* gp = &trow[p * CC + s * 8];
      float4 v0 = *(const float4*)gp;
      float4 v1 = *(const float4*)(gp + 4);
      ushort4 u0 = make_ushort4(f2bf(v0.x), f2bf(v0.y), f2bf(v0.z), f2bf(v0.w));
      ushort4 u1 = make_ushort4(f2bf(v1.x), f2bf(v1.y), f2bf(v1.z), f2bf(v1.w));
      uint4 pk;
      pk.x = (unsigned)u0.x | ((unsigned)u0.y << 16);
      pk.y = (unsigned)u0.z | ((unsigned)u0.w << 16);
      pk.z = (unsigned)u1.x | ((unsigned)u1.y << 16);
      pk.w = (unsigned)u1.z | ((unsigned)u1.w << 16);
      *(uint4*)(tsb + p * 512 + ((s ^ (p & 7)) << 4)) = pk;
    }
  }

  f32x4_t sc4 = (f32x4_t){0.f, 0.f, 0.f, 0.f};
  {
    const int lr = l & 15, lq = l >> 4;
    const unsigned short* qkrow = QKc + (size_t)t * 2048 + (size_t)(lr & 7) * 256;
#pragma unroll
    for (int es = 0; es < 8; es++) {
      int slot = es * 4 + lq;
      bf16x8_t aF = *(const bf16x8_t*)(tsb + lr * 512 + ((slot ^ (lr & 7)) << 4));
      bf16x8_t bF = *(const bf16x8_t*)&qkrow[es * 32 + lq * 8];
      sc4 = __builtin_amdgcn_mfma_f32_16x16x32_bf16(aF, bF, sc4, 0, 0, 0);
    }
  }

  {
    const int g = l >> 4;
    const float rsD = 0.17677669529663687f;
    float sc[4], cf[4];
#pragma unroll
    for (int j = 0; j < 4; j++) {
      int p = g * 4 + j;
      sc[j] = sc4[j] * wts[(size_t)t * PP + p] * rsD;
      cf[j] = conf[(size_t)t * PP + p];
    }
    float mx = fmaxf(fmaxf(sc[0], sc[1]), fmaxf(sc[2], sc[3]));
    mx = fmaxf(mx, __shfl_xor(mx, 16, 64));
    mx = fmaxf(mx, __shfl_xor(mx, 32, 64));
    float ex[4], sm = 0.f;
#pragma unroll
    for (int j = 0; j < 4; j++) { ex[j] = expf(sc[j] - mx); sm += ex[j]; }
    sm += __shfl_xor(sm, 16, 64);
    sm += __shfl_xor(sm, 32, 64);
    float inv = 1.f / sm;
    if ((l & 15) < 8) {
#pragma unroll
      for (int j = 0; j < 4; j++) awL[w][g * 4 + j][l & 15] = ex[j] * inv * cf[j];
    }
  }

  float tc[HH][4];
#pragma unroll
  for (int h = 0; h < HH; h++)
#pragma unroll
    for (int j = 0; j < 4; j++) tc[h][j] = 0.f;
#pragma unroll
  for (int p = 0; p < PP; p++) {
    uint2 tv = *(const uint2*)(tsb + p * 512 + (((l >> 1) ^ (p & 7)) << 4) + (l & 1) * 8);
    float te0 = bf2f((unsigned short)(tv.x & 0xffff));
    float te1 = bf2f((unsigned short)(tv.x >> 16));
    float te2 = bf2f((unsigned short)(tv.y & 0xffff));
    float te3 = bf2f((unsigned short)(tv.y >> 16));
#pragma unroll
    for (int h = 0; h < HH; h++) {
      float a = awL[w][p][h];
      tc[h][0] += a * te0; tc[h][1] += a * te1;
      tc[h][2] += a * te2; tc[h][3] += a * te3;
    }
  }
  size_t tcb = (size_t)t * 2048;
#pragma unroll
  for (int h = 0; h < HH; h++) {
    ushort4 o = make_ushort4(f2bf(tc[h][0]), f2bf(tc[h][1]), f2bf(tc[h][2]), f2bf(tc[h][3]));
    *(ushort4*)&TC[tcb + h * 256 + 4 * l] = o;
  }
}

// ---------------------------------------------------------------------------
// nwide GEMM (BM=32, BN=256, K=2048), 2-phase double-buffered.
// EPI: 0 = LN -> bf16; 1 = LN + residual -> f32.
// ---------------------------------------------------------------------------
template<int EPI>
__global__ __launch_bounds__(256) void nwide_gemm_kernel(
    const unsigned short* __restrict__ A, const unsigned short* __restrict__ Bt,
    unsigned short* __restrict__ OutB, float* __restrict__ OutF,
    const float* __restrict__ gam, const float* __restrict__ bet,
    const float* __restrict__ res) {
  __shared__ __align__(16) unsigned short As[2][32 * 32];
  __shared__ __align__(16) unsigned short Bs[2][256 * 32];
  __shared__ float redS[32][5], redQ[32][5];
  const int tid = threadIdx.x;
  const int wc = tid >> 6, l = tid & 63;
  const int lr = l & 15, lq = l >> 4;
  const int m0 = blockIdx.x * 32;
  const int K = 2048;

  f32x4_t acc[2][4];
#pragma unroll
  for (int m = 0; m < 2; m++)
#pragma unroll
    for (int n = 0; n < 4; n++) acc[m][n] = (f32x4_t){0.f, 0.f, 0.f, 0.f};

  const int rA = tid >> 2, sA = tid & 3, qA = sA ^ ((rA >> 1) & 3);

  if (tid < 128) gl_lds16(&A[(size_t)(m0 + rA) * K + qA * 8], &As[0][tid * 8]);
#pragma unroll
  for (int it = 0; it < 4; it++) {
    int lin = it * 256 + tid, r = lin >> 2, s = lin & 3, q = s ^ ((r >> 1) & 3);
    gl_lds16(&Bt[(size_t)r * K + q * 8], &Bs[0][lin * 8]);
  }
  __syncthreads();

  for (int st = 0; st < 64; st++) {
    int cur = st & 1;
    if (st < 63) {
      int kn = (st + 1) * 32;
      if (tid < 128) gl_lds16(&A[(size_t)(m0 + rA) * K + kn + qA * 8], &As[cur ^ 1][tid * 8]);
#pragma unroll
      for (int it = 0; it < 4; it++) {
        int lin = it * 256 + tid, r = lin >> 2, s = lin & 3, q = s ^ ((r >> 1) & 3);
        gl_lds16(&Bt[(size_t)r * K + kn + q * 8], &Bs[cur ^ 1][lin * 8]);
      }
    }
    bf16x8_t af[2], bfr[4];
#pragma unroll
    for (int m = 0; m < 2; m++) {
      int r = m * 16 + lr;
      int s = lq ^ ((r >> 1) & 3);
      af[m] = *(const bf16x8_t*)&As[cur][r * 32 + s * 8];
    }
#pragma unroll
    for (int n = 0; n < 4; n++) {
      int r = wc * 64 + n * 16 + lr;
      int s = lq ^ ((r >> 1) & 3);
      bfr[n] = *(const bf16x8_t*)&Bs[cur][r * 32 + s * 8];
    }
#pragma unroll
    for (int m = 0; m < 2; m++)
#pragma unroll
      for (int n = 0; n < 4; n++)
        acc[m][n] = __builtin_amdgcn_mfma_f32_16x16x32_bf16(af[m], bfr[n], acc[m][n], 0, 0, 0);
    __syncthreads();
  }

  // LN epilogue (block covers the full 256-col row)
  float s1[2][4], s2[2][4];
#pragma unroll
  for (int m = 0; m < 2; m++)
#pragma unroll
    for (int j = 0; j < 4; j++) {
      float a = 0.f, b = 0.f;
#pragma unroll
      for (int n = 0; n < 4; n++) { float x = acc[m][n][j]; a += x; b += x * x; }
      s1[m][j] = a; s2[m][j] = b;
    }
#pragma unroll
  for (int mask = 1; mask < 16; mask <<= 1)
#pragma unroll
    for (int m = 0; m < 2; m++)
#pragma unroll
      for (int j = 0; j < 4; j++) {
        s1[m][j] += __shfl_xor(s1[m][j], mask, 64);
        s2[m][j] += __shfl_xor(s2[m][j], mask, 64);
      }
  if (lr == 0) {
#pragma unroll
    for (int m = 0; m < 2; m++)
#pragma unroll
      for (int j = 0; j < 4; j++) {
        int rl = m * 16 + lq * 4 + j;
        redS[rl][wc] = s1[m][j];
        redQ[rl][wc] = s2[m][j];
      }
  }
  __syncthreads();
#pragma unroll
  for (int m = 0; m < 2; m++)
#pragma unroll
    for (int j = 0; j < 4; j++) {
      int rl = m * 16 + lq * 4 + j;
      float ts = redS[rl][0] + redS[rl][1] + redS[rl][2] + redS[rl][3];
      float tq = redQ[rl][0] + redQ[rl][1] + redQ[rl][2] + redQ[rl][3];
      float mu = ts * (1.f / 256.f);
      float var = tq * (1.f / 256.f) - mu * mu;
      float rs = rsqrtf(var + LN_EPS);
      size_t rowg = (size_t)(m0 + rl);
#pragma unroll
      for (int n = 0; n < 4; n++) {
        int col = wc * 64 + n * 16 + lr;
        float v = (acc[m][n][j] - mu) * rs * gam[col] + bet[col];
        if constexpr (EPI == 0) {
          OutB[rowg * CC + col] = f2bf(v);
        } else {
          OutF[rowg * CC + col] = res[rowg * CC + col] + v;
        }
      }
    }
}

// ---------------------------------------------------------------------------
// FFN GEMM1: hid = gelu([SB||MSG] @ W1t^T), bf16. BM=128 BN=128, 2-phase.
// ---------------------------------------------------------------------------
__global__ __launch_bounds__(256) void gemm1_kernel(
    const unsigned short* __restrict__ SB, const unsigned short* __restrict__ MSG,
    const unsigned short* __restrict__ W1t, unsigned short* __restrict__ hid) {
  __shared__ __align__(16) unsigned short As[2][128 * 32];
  __shared__ __align__(16) unsigned short Bs[2][128 * 32];
  const int tid = threadIdx.x;
  const int wv = tid >> 6, l = tid & 63;
  const int wr = wv >> 1, wc = wv & 1;
  const int lr = l & 15, lq = l >> 4;
  const int m0 = blockIdx.x * 128;
  const int n0 = blockIdx.y * 128;

  f32x4_t acc[4][4];
#pragma unroll
  for (int m = 0; m < 4; m++)
#pragma unroll
    for (int n = 0; n < 4; n++) acc[m][n] = (f32x4_t){0.f, 0.f, 0.f, 0.f};

#pragma unroll
  for (int it = 0; it < 2; it++) {   // prologue: step 0 (k<256 -> SB)
    int lin = it * 256 + tid, r = lin >> 2, s = lin & 3, q = s ^ ((r >> 1) & 3);
    gl_lds16(&SB[(size_t)(m0 + r) * CC + q * 8], &As[0][lin * 8]);
    gl_lds16(&W1t[(size_t)(n0 + r) * 512 + q * 8], &Bs[0][lin * 8]);
  }
  __syncthreads();

  for (int st = 0; st < 16; st++) {
    int cur = st & 1;
    if (st < 15) {
      int kn = (st + 1) * 32;
#pragma unroll
      for (int it = 0; it < 2; it++) {
        int lin = it * 256 + tid, r = lin >> 2, s = lin & 3, q = s ^ ((r >> 1) & 3);
        int ka = kn + q * 8;
        const unsigned short* ap = (ka < 256) ? &SB[(size_t)(m0 + r) * CC + ka]
                                              : &MSG[(size_t)(m0 + r) * CC + ka - 256];
        gl_lds16(ap, &As[cur ^ 1][lin * 8]);
        gl_lds16(&W1t[(size_t)(n0 + r) * 512 + kn + q * 8], &Bs[cur ^ 1][lin * 8]);
      }
    }
    bf16x8_t af[4], bf[4];
#pragma unroll
    for (int m = 0; m < 4; m++) {
      int r = wr * 64 + m * 16 + lr;
      int s = lq ^ ((r >> 1) & 3);
      af[m] = *(const bf16x8_t*)&As[cur][r * 32 + s * 8];
    }
#pragma unroll
    for (int n = 0; n < 4; n++) {
      int r = wc * 64 + n * 16 + lr;
      int s = lq ^ ((r >> 1) & 3);
      bf[n] = *(const bf16x8_t*)&Bs[cur][r * 32 + s * 8];
    }
#pragma unroll
    for (int m = 0; m < 4; m++)
#pragma unroll
      for (int n = 0; n < 4; n++)
        acc[m][n] = __builtin_amdgcn_mfma_f32_16x16x32_bf16(af[m], bf[n], acc[m][n], 0, 0, 0);
    __syncthreads();
  }

#pragma unroll
  for (int m = 0; m < 4; m++)
#pragma unroll
    for (int n = 0; n < 4; n++)
#pragma unroll
      for (int j = 0; j < 4; j++) {
        int row = m0 + wr * 64 + m * 16 + lq * 4 + j;
        int col = n0 + wc * 64 + n * 16 + lr;
        float x = acc[m][n][j];
        float gl = 0.5f * x * (1.0f + erff(x * 0.70710678118654752f));
        hid[(size_t)row * 2048 + col] = f2bf(gl);
      }
}

extern "C" void kernel_launch(void* const* d_in, const int* in_sizes, int n_in,
                              void* d_out, int out_size, void* d_ws, size_t ws_size,
                              hipStream_t stream) {
  const float* source = (const float*)d_in[0];
  const float* target = (const float*)d_in[1];
  const float* weights = (const float*)d_in[2];
  const float* conf   = (const float*)d_in[3];
  const float* Wq = (const float*)d_in[4];
  const float* Wk = (const float*)d_in[5];
  const float* Wv = (const float*)d_in[6];
  const float* Wm = (const float*)d_in[7];
  const float* g1 = (const float*)d_in[8];
  const float* b1 = (const float*)d_in[9];
  const float* Wf1 = (const float*)d_in[10];
  const float* Wf2 = (const float*)d_in[11];
  const float* g2 = (const float*)d_in[12];
  const float* b2 = (const float*)d_in[13];
  float* out = (float*)d_out;

  unsigned short* SB   = (unsigned short*)d_ws;                 // [16384][256]
  unsigned short* MSGb = SB + (size_t)T_TOK * CC;               // [16384][256]
  unsigned short* Mt   = MSGb + (size_t)T_TOK * CC;             // [2048][256]
  unsigned short* WVMt = Mt + (size_t)2048 * 256;               // [256][2048]
  unsigned short* WF1t = WVMt + (size_t)256 * 2048;             // [2048][512]
  unsigned short* WF2t = WF1t + (size_t)2048 * 512;             // [256][2048]
  unsigned short* BIG1 = WF2t + (size_t)256 * 2048;             // QKc, later hid
  unsigned short* BIG2 = BIG1 + (size_t)T_TOK * 2048;           // TC
  unsigned short* QKc  = BIG1;
  unsigned short* hid  = BIG1;
  unsigned short* TC   = BIG2;

  // prep
  cvt_bf16_kernel<<<T_TOK * CC / 1024, 256, 0, stream>>>(source, SB);
  transpose_cvt_kernel<<<dim3(8, 32), 256, 0, stream>>>(Wf1, WF1t, 512, 2048);
  transpose_cvt_kernel<<<dim3(32, 4), 256, 0, stream>>>(Wf2, WF2t, 2048, 256);
  precM_kernel<<<16, 256, 0, stream>>>(Wq, Wk, Mt);
  precWVM_kernel<<<8, 256, 0, stream>>>(Wv, Wm, WVMt);

  // attention pipeline
  qk_gemm_kernel<<<dim3(T_TOK / 64, 8), 512, 0, stream>>>(SB, Mt, QKc, 256, 2048);
  attn2_kernel<<<T_TOK / 4, 256, 0, stream>>>(QKc, target, weights, conf, TC);
  // message = LN(TC @ WVMt^T)
  nwide_gemm_kernel<0><<<T_TOK / 32, 256, 0, stream>>>(
      TC, WVMt, MSGb, nullptr, g1, b1, nullptr);

  // FFN
  gemm1_kernel<<<dim3(T_TOK / 128, 16), 256, 0, stream>>>(SB, MSGb, WF1t, hid);
  // out = src + LN(hid @ W2t^T)
  nwide_gemm_kernel<1><<<T_TOK / 32, 256, 0, stream>>>(
      hid, WF2t, nullptr, out, g2, b2, source);
}

// Round 9
// 365.359 us; speedup vs baseline: 1.0080x; 1.0080x over previous
//
#include <hip/hip_runtime.h>
#include <hip/hip_bf16.h>
#include <math.h>

#define T_TOK 16384
#define CC 256
#define PP 16
#define HH 8
#define DD 32
#define LN_EPS 1e-5f

typedef __attribute__((ext_vector_type(8))) short bf16x8_t;
typedef __attribute__((ext_vector_type(4))) float f32x4_t;

__device__ __forceinline__ unsigned short f2bf(float x) {
  __hip_bfloat16 h = __float2bfloat16(x);
  return *reinterpret_cast<unsigned short*>(&h);
}
__device__ __forceinline__ float bf2f(unsigned short u) {
  union { unsigned int i; float f; } v; v.i = ((unsigned int)u) << 16; return v.f;
}
// async global->LDS, 16B per lane; LDS dest must be wave-uniform base + lane*16
__device__ __forceinline__ void gl_lds16(const unsigned short* g, unsigned short* l) {
  __builtin_amdgcn_global_load_lds(
      (const __attribute__((address_space(1))) unsigned int*)g,
      (__attribute__((address_space(3))) unsigned int*)l, 16, 0, 0);
}

// ---------------------------------------------------------------------------
// Prep kernels
// ---------------------------------------------------------------------------
__global__ __launch_bounds__(256) void cvt_bf16_kernel(const float* __restrict__ src,
                                                       unsigned short* __restrict__ dst) {
  int i = (blockIdx.x * 256 + threadIdx.x) * 4;
  float4 v = *(const float4*)&src[i];
  ushort4 o = make_ushort4(f2bf(v.x), f2bf(v.y), f2bf(v.z), f2bf(v.w));
  *(ushort4*)&dst[i] = o;
}

__global__ __launch_bounds__(256) void transpose_cvt_kernel(const float* __restrict__ src,
                                                            unsigned short* __restrict__ dst,
                                                            int K, int N) {
  __shared__ float tile[64][65];
  int k0 = blockIdx.x * 64, n0 = blockIdx.y * 64;
  int tid = threadIdx.x;
#pragma unroll
  for (int i = 0; i < 16; i++) {
    int lin = i * 256 + tid, r = lin >> 6, c = lin & 63;
    tile[r][c] = src[(size_t)(k0 + r) * N + n0 + c];
  }
  __syncthreads();
#pragma unroll
  for (int i = 0; i < 16; i++) {
    int lin = i * 256 + tid, n = lin >> 6, k = lin & 63;
    dst[(size_t)(n0 + n) * K + k0 + k] = f2bf(tile[k][n]);
  }
}

// Mt[(h*256+e)][c] = bf16( sum_d Wq[c][h*32+d] * Wk[e][h*32+d] )
__global__ __launch_bounds__(256) void precM_kernel(const float* __restrict__ Wq,
                                                    const float* __restrict__ Wk,
                                                    unsigned short* __restrict__ Mt) {
  __shared__ float wqS[256][33];
  __shared__ float wkS[128][33];
  const int tid = threadIdx.x;
  const int h = blockIdx.x >> 1, eh = blockIdx.x & 1;
#pragma unroll
  for (int it = 0; it < 32; it++) {
    int lin = it * 256 + tid, r = lin >> 5, d = lin & 31;
    wqS[r][d] = Wq[(size_t)r * CC + h * DD + d];
  }
#pragma unroll
  for (int it = 0; it < 16; it++) {
    int lin = it * 256 + tid, r = lin >> 5, d = lin & 31;
    wkS[r][d] = Wk[(size_t)(eh * 128 + r) * CC + h * DD + d];
  }
  __syncthreads();
  const int w = tid >> 6, l = tid & 63;
  for (int ei = 0; ei < 32; ei++) {
    int e = w * 32 + ei;
    float o[4] = {0.f, 0.f, 0.f, 0.f};
#pragma unroll
    for (int d = 0; d < 32; d++) {
      float kv = wkS[e][d];
      o[0] += kv * wqS[l][d];
      o[1] += kv * wqS[l + 64][d];
      o[2] += kv * wqS[l + 128][d];
      o[3] += kv * wqS[l + 192][d];
    }
    size_t rowb = (size_t)(h * 256 + eh * 128 + e) * CC;
    Mt[rowb + l] = f2bf(o[0]);
    Mt[rowb + l + 64] = f2bf(o[1]);
    Mt[rowb + l + 128] = f2bf(o[2]);
    Mt[rowb + l + 192] = f2bf(o[3]);
  }
}

// WVMt[c][h*256+e] = bf16( sum_d Wv[e][h*32+d] * Wm[h*32+d][c] ); grid = 8 (h)
__global__ __launch_bounds__(256) void precWVM_kernel(const float* __restrict__ Wv,
                                                      const float* __restrict__ Wm,
                                                      unsigned short* __restrict__ WVMt) {
  __shared__ float WvS[256][33];
  __shared__ float WmS[32][257];
  const int h = blockIdx.x;
  const int tid = threadIdx.x;
#pragma unroll
  for (int it = 0; it < 32; it++) {
    int lin = it * 256 + tid, e = lin >> 5, d = lin & 31;
    WvS[e][d] = Wv[(size_t)e * CC + h * DD + d];
  }
#pragma unroll
  for (int it = 0; it < 32; it++) {
    int lin = it * 256 + tid, d = lin >> 8, c = lin & 255;
    WmS[d][c] = Wm[(size_t)(h * DD + d) * CC + c];
  }
  __syncthreads();
  float wm[32];
#pragma unroll
  for (int d = 0; d < 32; d++) wm[d] = WmS[d][tid];
  for (int e = 0; e < 256; e++) {
    float acc = 0.f;
#pragma unroll
    for (int d = 0; d < 32; d++) acc += WvS[e][d] * wm[d];
    WVMt[(size_t)tid * 2048 + h * 256 + e] = f2bf(acc);
  }
}

// ---------------------------------------------------------------------------
// gemm128: Out[M, strideO] = A(||A2) [M,K] @ Bt^T  (Bt [N][K] bf16).
// BM=BN=128, 256 thr = 4 waves (2x2), wave tile 64x64 (4x4 frags), m97-style
// single-buffer 2-barrier K-loop with global_load_lds staging.
// A row stride is 256 (concat: k<256 from A, else from A2).
// EPI 0: plain bf16 store. EPI 1: gelu -> bf16 store.
// ---------------------------------------------------------------------------
template<int EPI>
__global__ __launch_bounds__(256) void gemm128_kernel(
    const unsigned short* __restrict__ A, const unsigned short* __restrict__ A2,
    const unsigned short* __restrict__ Bt, unsigned short* __restrict__ Out,
    int K, int strideO) {
  __shared__ __align__(16) unsigned short As[128 * 32];
  __shared__ __align__(16) unsigned short Bs[128 * 32];
  const int tid = threadIdx.x;
  const int wv = tid >> 6, l = tid & 63;
  const int wr = wv >> 1, wc = wv & 1;
  const int lr = l & 15, lq = l >> 4;
  const int m0 = blockIdx.x * 128;
  const int n0 = blockIdx.y * 128;
  const int nsteps = K >> 5;

  f32x4_t acc[4][4];
#pragma unroll
  for (int m = 0; m < 4; m++)
#pragma unroll
    for (int n = 0; n < 4; n++) acc[m][n] = (f32x4_t){0.f, 0.f, 0.f, 0.f};

  for (int st = 0; st < nsteps; st++) {
    int kn = st * 32;
#pragma unroll
    for (int it = 0; it < 2; it++) {
      int lin = it * 256 + tid, r = lin >> 2, s = lin & 3, q = s ^ ((r >> 1) & 3);
      int ka = kn + q * 8;
      const unsigned short* ap = (ka < 256) ? &A[(size_t)(m0 + r) * CC + ka]
                                            : &A2[(size_t)(m0 + r) * CC + ka - 256];
      gl_lds16(ap, &As[lin * 8]);
      gl_lds16(&Bt[(size_t)(n0 + r) * K + kn + q * 8], &Bs[lin * 8]);
    }
    __syncthreads();
    bf16x8_t af[4], bf[4];
#pragma unroll
    for (int m = 0; m < 4; m++) {
      int r = wr * 64 + m * 16 + lr;
      int s = lq ^ ((r >> 1) & 3);
      af[m] = *(const bf16x8_t*)&As[r * 32 + s * 8];
    }
#pragma unroll
    for (int n = 0; n < 4; n++) {
      int r = wc * 64 + n * 16 + lr;
      int s = lq ^ ((r >> 1) & 3);
      bf[n] = *(const bf16x8_t*)&Bs[r * 32 + s * 8];
    }
#pragma unroll
    for (int m = 0; m < 4; m++)
#pragma unroll
      for (int n = 0; n < 4; n++)
        acc[m][n] = __builtin_amdgcn_mfma_f32_16x16x32_bf16(af[m], bf[n], acc[m][n], 0, 0, 0);
    __syncthreads();
  }

#pragma unroll
  for (int m = 0; m < 4; m++)
#pragma unroll
    for (int n = 0; n < 4; n++)
#pragma unroll
      for (int j = 0; j < 4; j++) {
        int row = m0 + wr * 64 + m * 16 + lq * 4 + j;
        int col = n0 + wc * 64 + n * 16 + lr;
        float x = acc[m][n][j];
        if constexpr (EPI == 1)
          x = 0.5f * x * (1.0f + erff(x * 0.70710678118654752f));
        Out[(size_t)row * strideO + col] = f2bf(x);
      }
}

// ---------------------------------------------------------------------------
// attn2: per wave = one token. T tile f32->bf16 in swizzled LDS; scores via
// 8 MFMAs; softmax on 4 regs + 2 shuffles; combine from LDS; writes TC bf16.
// ---------------------------------------------------------------------------
__global__ __launch_bounds__(256) void attn2_kernel(const unsigned short* __restrict__ QKc,
                                                    const float* __restrict__ target,
                                                    const float* __restrict__ wts,
                                                    const float* __restrict__ conf,
                                                    unsigned short* __restrict__ TC) {
  __shared__ __align__(16) unsigned short Ts[4][16 * 256];
  __shared__ float awL[4][PP][HH];
  const int tid = threadIdx.x;
  const int w = tid >> 6, l = tid & 63;
  const int t = blockIdx.x * 4 + w;
  const float* trow = target + (size_t)t * PP * CC;
  char* tsb = (char*)&Ts[w][0];

  {
    const int p = l >> 2;
#pragma unroll
    for (int i = 0; i < 8; i++) {
      int s = (l & 3) + i * 4;
      const float* gp = &trow[p * CC + s * 8];
      float4 v0 = *(const float4*)gp;
      float4 v1 = *(const float4*)(gp + 4);
      ushort4 u0 = make_ushort4(f2bf(v0.x), f2bf(v0.y), f2bf(v0.z), f2bf(v0.w));
      ushort4 u1 = make_ushort4(f2bf(v1.x), f2bf(v1.y), f2bf(v1.z), f2bf(v1.w));
      uint4 pk;
      pk.x = (unsigned)u0.x | ((unsigned)u0.y << 16);
      pk.y = (unsigned)u0.z | ((unsigned)u0.w << 16);
      pk.z = (unsigned)u1.x | ((unsigned)u1.y << 16);
      pk.w = (unsigned)u1.z | ((unsigned)u1.w << 16);
      *(uint4*)(tsb + p * 512 + ((s ^ (p & 7)) << 4)) = pk;
    }
  }

  f32x4_t sc4 = (f32x4_t){0.f, 0.f, 0.f, 0.f};
  {
    const int lr = l & 15, lq = l >> 4;
    const unsigned short* qkrow = QKc + (size_t)t * 2048 + (size_t)(lr & 7) * 256;
#pragma unroll
    for (int es = 0; es < 8; es++) {
      int slot = es * 4 + lq;
      bf16x8_t aF = *(const bf16x8_t*)(tsb + lr * 512 + ((slot ^ (lr & 7)) << 4));
      bf16x8_t bF = *(const bf16x8_t*)&qkrow[es * 32 + lq * 8];
      sc4 = __builtin_amdgcn_mfma_f32_16x16x32_bf16(aF, bF, sc4, 0, 0, 0);
    }
  }

  {
    const int g = l >> 4;
    const float rsD = 0.17677669529663687f;
    float sc[4], cf[4];
#pragma unroll
    for (int j = 0; j < 4; j++) {
      int p = g * 4 + j;
      sc[j] = sc4[j] * wts[(size_t)t * PP + p] * rsD;
      cf[j] = conf[(size_t)t * PP + p];
    }
    float mx = fmaxf(fmaxf(sc[0], sc[1]), fmaxf(sc[2], sc[3]));
    mx = fmaxf(mx, __shfl_xor(mx, 16, 64));
    mx = fmaxf(mx, __shfl_xor(mx, 32, 64));
    float ex[4], sm = 0.f;
#pragma unroll
    for (int j = 0; j < 4; j++) { ex[j] = expf(sc[j] - mx); sm += ex[j]; }
    sm += __shfl_xor(sm, 16, 64);
    sm += __shfl_xor(sm, 32, 64);
    float inv = 1.f / sm;
    if ((l & 15) < 8) {
#pragma unroll
      for (int j = 0; j < 4; j++) awL[w][g * 4 + j][l & 15] = ex[j] * inv * cf[j];
    }
  }

  float tc[HH][4];
#pragma unroll
  for (int h = 0; h < HH; h++)
#pragma unroll
    for (int j = 0; j < 4; j++) tc[h][j] = 0.f;
#pragma unroll
  for (int p = 0; p < PP; p++) {
    uint2 tv = *(const uint2*)(tsb + p * 512 + (((l >> 1) ^ (p & 7)) << 4) + (l & 1) * 8);
    float te0 = bf2f((unsigned short)(tv.x & 0xffff));
    float te1 = bf2f((unsigned short)(tv.x >> 16));
    float te2 = bf2f((unsigned short)(tv.y & 0xffff));
    float te3 = bf2f((unsigned short)(tv.y >> 16));
#pragma unroll
    for (int h = 0; h < HH; h++) {
      float a = awL[w][p][h];
      tc[h][0] += a * te0; tc[h][1] += a * te1;
      tc[h][2] += a * te2; tc[h][3] += a * te3;
    }
  }
  size_t tcb = (size_t)t * 2048;
#pragma unroll
  for (int h = 0; h < HH; h++) {
    ushort4 o = make_ushort4(f2bf(tc[h][0]), f2bf(tc[h][1]), f2bf(tc[h][2]), f2bf(tc[h][3]));
    *(ushort4*)&TC[tcb + h * 256 + 4 * l] = o;
  }
}

// ---------------------------------------------------------------------------
// nwide GEMM (BM=32, BN=256, K=2048), single-buffer m97-style.
// EPI: 0 = LN -> bf16; 1 = LN + residual -> f32.
// ---------------------------------------------------------------------------
template<int EPI>
__global__ __launch_bounds__(256) void nwide_gemm_kernel(
    const unsigned short* __restrict__ A, const unsigned short* __restrict__ Bt,
    unsigned short* __restrict__ OutB, float* __restrict__ OutF,
    const float* __restrict__ gam, const float* __restrict__ bet,
    const float* __restrict__ res) {
  __shared__ __align__(16) unsigned short As[32 * 32];
  __shared__ __align__(16) unsigned short Bs[256 * 32];
  __shared__ float redS[32][5], redQ[32][5];
  const int tid = threadIdx.x;
  const int wc = tid >> 6, l = tid & 63;
  const int lr = l & 15, lq = l >> 4;
  const int m0 = blockIdx.x * 32;
  const int K = 2048;

  f32x4_t acc[2][4];
#pragma unroll
  for (int m = 0; m < 2; m++)
#pragma unroll
    for (int n = 0; n < 4; n++) acc[m][n] = (f32x4_t){0.f, 0.f, 0.f, 0.f};

  const int rA = tid >> 2, sA = tid & 3, qA = sA ^ ((rA >> 1) & 3);

  for (int st = 0; st < 64; st++) {
    int kn = st * 32;
    if (tid < 128) gl_lds16(&A[(size_t)(m0 + rA) * K + kn + qA * 8], &As[tid * 8]);
#pragma unroll
    for (int it = 0; it < 4; it++) {
      int lin = it * 256 + tid, r = lin >> 2, s = lin & 3, q = s ^ ((r >> 1) & 3);
      gl_lds16(&Bt[(size_t)r * K + kn + q * 8], &Bs[lin * 8]);
    }
    __syncthreads();
    bf16x8_t af[2], bfr[4];
#pragma unroll
    for (int m = 0; m < 2; m++) {
      int r = m * 16 + lr;
      int s = lq ^ ((r >> 1) & 3);
      af[m] = *(const bf16x8_t*)&As[r * 32 + s * 8];
    }
#pragma unroll
    for (int n = 0; n < 4; n++) {
      int r = wc * 64 + n * 16 + lr;
      int s = lq ^ ((r >> 1) & 3);
      bfr[n] = *(const bf16x8_t*)&Bs[r * 32 + s * 8];
    }
#pragma unroll
    for (int m = 0; m < 2; m++)
#pragma unroll
      for (int n = 0; n < 4; n++)
        acc[m][n] = __builtin_amdgcn_mfma_f32_16x16x32_bf16(af[m], bfr[n], acc[m][n], 0, 0, 0);
    __syncthreads();
  }

  // LN epilogue (block covers the full 256-col row)
  float s1[2][4], s2[2][4];
#pragma unroll
  for (int m = 0; m < 2; m++)
#pragma unroll
    for (int j = 0; j < 4; j++) {
      float a = 0.f, b = 0.f;
#pragma unroll
      for (int n = 0; n < 4; n++) { float x = acc[m][n][j]; a += x; b += x * x; }
      s1[m][j] = a; s2[m][j] = b;
    }
#pragma unroll
  for (int mask = 1; mask < 16; mask <<= 1)
#pragma unroll
    for (int m = 0; m < 2; m++)
#pragma unroll
      for (int j = 0; j < 4; j++) {
        s1[m][j] += __shfl_xor(s1[m][j], mask, 64);
        s2[m][j] += __shfl_xor(s2[m][j], mask, 64);
      }
  if (lr == 0) {
#pragma unroll
    for (int m = 0; m < 2; m++)
#pragma unroll
      for (int j = 0; j < 4; j++) {
        int rl = m * 16 + lq * 4 + j;
        redS[rl][wc] = s1[m][j];
        redQ[rl][wc] = s2[m][j];
      }
  }
  __syncthreads();
#pragma unroll
  for (int m = 0; m < 2; m++)
#pragma unroll
    for (int j = 0; j < 4; j++) {
      int rl = m * 16 + lq * 4 + j;
      float ts = redS[rl][0] + redS[rl][1] + redS[rl][2] + redS[rl][3];
      float tq = redQ[rl][0] + redQ[rl][1] + redQ[rl][2] + redQ[rl][3];
      float mu = ts * (1.f / 256.f);
      float var = tq * (1.f / 256.f) - mu * mu;
      float rs = rsqrtf(var + LN_EPS);
      size_t rowg = (size_t)(m0 + rl);
#pragma unroll
      for (int n = 0; n < 4; n++) {
        int col = wc * 64 + n * 16 + lr;
        float v = (acc[m][n][j] - mu) * rs * gam[col] + bet[col];
        if constexpr (EPI == 0) {
          OutB[rowg * CC + col] = f2bf(v);
        } else {
          OutF[rowg * CC + col] = res[rowg * CC + col] + v;
        }
      }
    }
}

extern "C" void kernel_launch(void* const* d_in, const int* in_sizes, int n_in,
                              void* d_out, int out_size, void* d_ws, size_t ws_size,
                              hipStream_t stream) {
  const float* source = (const float*)d_in[0];
  const float* target = (const float*)d_in[1];
  const float* weights = (const float*)d_in[2];
  const float* conf   = (const float*)d_in[3];
  const float* Wq = (const float*)d_in[4];
  const float* Wk = (const float*)d_in[5];
  const float* Wv = (const float*)d_in[6];
  const float* Wm = (const float*)d_in[7];
  const float* g1 = (const float*)d_in[8];
  const float* b1 = (const float*)d_in[9];
  const float* Wf1 = (const float*)d_in[10];
  const float* Wf2 = (const float*)d_in[11];
  const float* g2 = (const float*)d_in[12];
  const float* b2 = (const float*)d_in[13];
  float* out = (float*)d_out;

  unsigned short* SB   = (unsigned short*)d_ws;                 // [16384][256]
  unsigned short* MSGb = SB + (size_t)T_TOK * CC;               // [16384][256]
  unsigned short* Mt   = MSGb + (size_t)T_TOK * CC;             // [2048][256]
  unsigned short* WVMt = Mt + (size_t)2048 * 256;               // [256][2048]
  unsigned short* WF1t = WVMt + (size_t)256 * 2048;             // [2048][512]
  unsigned short* WF2t = WF1t + (size_t)2048 * 512;             // [256][2048]
  unsigned short* BIG1 = WF2t + (size_t)256 * 2048;             // QKc, later hid
  unsigned short* BIG2 = BIG1 + (size_t)T_TOK * 2048;           // TC
  unsigned short* QKc  = BIG1;
  unsigned short* hid  = BIG1;
  unsigned short* TC   = BIG2;

  // prep
  cvt_bf16_kernel<<<T_TOK * CC / 1024, 256, 0, stream>>>(source, SB);
  transpose_cvt_kernel<<<dim3(8, 32), 256, 0, stream>>>(Wf1, WF1t, 512, 2048);
  transpose_cvt_kernel<<<dim3(32, 4), 256, 0, stream>>>(Wf2, WF2t, 2048, 256);
  precM_kernel<<<16, 256, 0, stream>>>(Wq, Wk, Mt);
  precWVM_kernel<<<8, 256, 0, stream>>>(Wv, Wm, WVMt);

  // attention pipeline: QKc = SB @ Mt^T  (128x128 tiles)
  gemm128_kernel<0><<<dim3(T_TOK / 128, 16), 256, 0, stream>>>(
      SB, SB, Mt, QKc, 256, 2048);
  attn2_kernel<<<T_TOK / 4, 256, 0, stream>>>(QKc, target, weights, conf, TC);
  // message = LN(TC @ WVMt^T)
  nwide_gemm_kernel<0><<<T_TOK / 32, 256, 0, stream>>>(
      TC, WVMt, MSGb, nullptr, g1, b1, nullptr);

  // FFN: hid = gelu([SB||MSG] @ W1t^T)  (128x128 tiles)
  gemm128_kernel<1><<<dim3(T_TOK / 128, 16), 256, 0, stream>>>(
      SB, MSGb, WF1t, hid, 512, 2048);
  // out = src + LN(hid @ W2t^T)
  nwide_gemm_kernel<1><<<T_TOK / 32, 256, 0, stream>>>(
      hid, WF2t, nullptr, out, g2, b2, source);
}

// Round 10
// 353.357 us; speedup vs baseline: 1.0422x; 1.0340x over previous
//
#include <hip/hip_runtime.h>
#include <hip/hip_bf16.h>
#include <math.h>

#define T_TOK 16384
#define CC 256
#define PP 16
#define HH 8
#define DD 32
#define LN_EPS 1e-5f

typedef __attribute__((ext_vector_type(8))) short bf16x8_t;
typedef __attribute__((ext_vector_type(4))) float f32x4_t;

__device__ __forceinline__ unsigned short f2bf(float x) {
  __hip_bfloat16 h = __float2bfloat16(x);
  return *reinterpret_cast<unsigned short*>(&h);
}
__device__ __forceinline__ float bf2f(unsigned short u) {
  union { unsigned int i; float f; } v; v.i = ((unsigned int)u) << 16; return v.f;
}
// async global->LDS, 16B per lane; LDS dest must be wave-uniform base + lane*16
__device__ __forceinline__ void gl_lds16(const unsigned short* g, unsigned short* l) {
  __builtin_amdgcn_global_load_lds(
      (const __attribute__((address_space(1))) unsigned int*)g,
      (__attribute__((address_space(3))) unsigned int*)l, 16, 0, 0);
}

// ---------------------------------------------------------------------------
// Prep kernels
// ---------------------------------------------------------------------------
__global__ __launch_bounds__(256) void cvt_bf16_kernel(const float* __restrict__ src,
                                                       unsigned short* __restrict__ dst) {
  int i = (blockIdx.x * 256 + threadIdx.x) * 4;
  float4 v = *(const float4*)&src[i];
  ushort4 o = make_ushort4(f2bf(v.x), f2bf(v.y), f2bf(v.z), f2bf(v.w));
  *(ushort4*)&dst[i] = o;
}

__global__ __launch_bounds__(256) void transpose_cvt_kernel(const float* __restrict__ src,
                                                            unsigned short* __restrict__ dst,
                                                            int K, int N) {
  __shared__ float tile[64][65];
  int k0 = blockIdx.x * 64, n0 = blockIdx.y * 64;
  int tid = threadIdx.x;
#pragma unroll
  for (int i = 0; i < 16; i++) {
    int lin = i * 256 + tid, r = lin >> 6, c = lin & 63;
    tile[r][c] = src[(size_t)(k0 + r) * N + n0 + c];
  }
  __syncthreads();
#pragma unroll
  for (int i = 0; i < 16; i++) {
    int lin = i * 256 + tid, n = lin >> 6, k = lin & 63;
    dst[(size_t)(n0 + n) * K + k0 + k] = f2bf(tile[k][n]);
  }
}

// Mt[(h*256+e)][c] = bf16( sum_d Wq[c][h*32+d] * Wk[e][h*32+d] )
__global__ __launch_bounds__(256) void precM_kernel(const float* __restrict__ Wq,
                                                    const float* __restrict__ Wk,
                                                    unsigned short* __restrict__ Mt) {
  __shared__ float wqS[256][33];
  __shared__ float wkS[128][33];
  const int tid = threadIdx.x;
  const int h = blockIdx.x >> 1, eh = blockIdx.x & 1;
#pragma unroll
  for (int it = 0; it < 32; it++) {
    int lin = it * 256 + tid, r = lin >> 5, d = lin & 31;
    wqS[r][d] = Wq[(size_t)r * CC + h * DD + d];
  }
#pragma unroll
  for (int it = 0; it < 16; it++) {
    int lin = it * 256 + tid, r = lin >> 5, d = lin & 31;
    wkS[r][d] = Wk[(size_t)(eh * 128 + r) * CC + h * DD + d];
  }
  __syncthreads();
  const int w = tid >> 6, l = tid & 63;
  for (int ei = 0; ei < 32; ei++) {
    int e = w * 32 + ei;
    float o[4] = {0.f, 0.f, 0.f, 0.f};
#pragma unroll
    for (int d = 0; d < 32; d++) {
      float kv = wkS[e][d];
      o[0] += kv * wqS[l][d];
      o[1] += kv * wqS[l + 64][d];
      o[2] += kv * wqS[l + 128][d];
      o[3] += kv * wqS[l + 192][d];
    }
    size_t rowb = (size_t)(h * 256 + eh * 128 + e) * CC;
    Mt[rowb + l] = f2bf(o[0]);
    Mt[rowb + l + 64] = f2bf(o[1]);
    Mt[rowb + l + 128] = f2bf(o[2]);
    Mt[rowb + l + 192] = f2bf(o[3]);
  }
}

// WVMt[c][h*256+e] = bf16( sum_d Wv[e][h*32+d] * Wm[h*32+d][c] ); grid = 8 (h)
__global__ __launch_bounds__(256) void precWVM_kernel(const float* __restrict__ Wv,
                                                      const float* __restrict__ Wm,
                                                      unsigned short* __restrict__ WVMt) {
  __shared__ float WvS[256][33];
  __shared__ float WmS[32][257];
  const int h = blockIdx.x;
  const int tid = threadIdx.x;
#pragma unroll
  for (int it = 0; it < 32; it++) {
    int lin = it * 256 + tid, e = lin >> 5, d = lin & 31;
    WvS[e][d] = Wv[(size_t)e * CC + h * DD + d];
  }
#pragma unroll
  for (int it = 0; it < 32; it++) {
    int lin = it * 256 + tid, d = lin >> 8, c = lin & 255;
    WmS[d][c] = Wm[(size_t)(h * DD + d) * CC + c];
  }
  __syncthreads();
  float wm[32];
#pragma unroll
  for (int d = 0; d < 32; d++) wm[d] = WmS[d][tid];
  for (int e = 0; e < 256; e++) {
    float acc = 0.f;
#pragma unroll
    for (int d = 0; d < 32; d++) acc += WvS[e][d] * wm[d];
    WVMt[(size_t)tid * 2048 + h * 256 + e] = f2bf(acc);
  }
}

// ---------------------------------------------------------------------------
// QK GEMM (round-7 proven shape): Out = A[M,256] @ Bt^T, BM=64 BN=256 BK=32,
// 512 thr, single-buffer m97 structure with global_load_lds staging.
// ---------------------------------------------------------------------------
__global__ __launch_bounds__(512) void qk_gemm_kernel(
    const unsigned short* __restrict__ A, const unsigned short* __restrict__ Bt,
    unsigned short* __restrict__ Out, int K, int strideO) {
  __shared__ __align__(16) unsigned short As[64 * 32];
  __shared__ __align__(16) unsigned short Bs[256 * 32];
  const int tid = threadIdx.x;
  const int wv = tid >> 6, l = tid & 63;
  const int wr = wv >> 2, wc = wv & 3;
  const int lr = l & 15, lq = l >> 4;
  const int m0 = blockIdx.x * 64;
  const int n0 = blockIdx.y * 256;
  const int nsteps = K >> 5;

  f32x4_t acc[2][4];
#pragma unroll
  for (int m = 0; m < 2; m++)
#pragma unroll
    for (int n = 0; n < 4; n++) acc[m][n] = (f32x4_t){0.f, 0.f, 0.f, 0.f};

  const int rA = tid >> 2, sA = tid & 3, qA = sA ^ ((rA >> 1) & 3);

  for (int st = 0; st < nsteps; st++) {
    int kn = st * 32;
    if (tid < 256) gl_lds16(&A[(size_t)(m0 + rA) * K + kn + qA * 8], &As[tid * 8]);
#pragma unroll
    for (int it = 0; it < 2; it++) {
      int lin = it * 512 + tid, r = lin >> 2, s = lin & 3, q = s ^ ((r >> 1) & 3);
      gl_lds16(&Bt[(size_t)(n0 + r) * K + kn + q * 8], &Bs[lin * 8]);
    }
    __syncthreads();
    bf16x8_t af[2], bfr[4];
#pragma unroll
    for (int m = 0; m < 2; m++) {
      int r = wr * 32 + m * 16 + lr;
      int s = lq ^ ((r >> 1) & 3);
      af[m] = *(const bf16x8_t*)&As[r * 32 + s * 8];
    }
#pragma unroll
    for (int n = 0; n < 4; n++) {
      int r = wc * 64 + n * 16 + lr;
      int s = lq ^ ((r >> 1) & 3);
      bfr[n] = *(const bf16x8_t*)&Bs[r * 32 + s * 8];
    }
#pragma unroll
    for (int m = 0; m < 2; m++)
#pragma unroll
      for (int n = 0; n < 4; n++)
        acc[m][n] = __builtin_amdgcn_mfma_f32_16x16x32_bf16(af[m], bfr[n], acc[m][n], 0, 0, 0);
    __syncthreads();
  }

#pragma unroll
  for (int m = 0; m < 2; m++)
#pragma unroll
    for (int n = 0; n < 4; n++)
#pragma unroll
      for (int j = 0; j < 4; j++) {
        int rl = wr * 32 + m * 16 + lq * 4 + j;
        int col = n0 + wc * 64 + n * 16 + lr;
        Out[(size_t)(m0 + rl) * strideO + col] = f2bf(acc[m][n][j]);
      }
}

// ---------------------------------------------------------------------------
// gemm128: hid = gelu([A||A2][M,K] @ Bt^T). BM=BN=128, 256 thr, single-buffer.
// ---------------------------------------------------------------------------
__global__ __launch_bounds__(256) void gemm128_kernel(
    const unsigned short* __restrict__ A, const unsigned short* __restrict__ A2,
    const unsigned short* __restrict__ Bt, unsigned short* __restrict__ Out,
    int K, int strideO) {
  __shared__ __align__(16) unsigned short As[128 * 32];
  __shared__ __align__(16) unsigned short Bs[128 * 32];
  const int tid = threadIdx.x;
  const int wv = tid >> 6, l = tid & 63;
  const int wr = wv >> 1, wc = wv & 1;
  const int lr = l & 15, lq = l >> 4;
  const int m0 = blockIdx.x * 128;
  const int n0 = blockIdx.y * 128;
  const int nsteps = K >> 5;

  f32x4_t acc[4][4];
#pragma unroll
  for (int m = 0; m < 4; m++)
#pragma unroll
    for (int n = 0; n < 4; n++) acc[m][n] = (f32x4_t){0.f, 0.f, 0.f, 0.f};

  for (int st = 0; st < nsteps; st++) {
    int kn = st * 32;
#pragma unroll
    for (int it = 0; it < 2; it++) {
      int lin = it * 256 + tid, r = lin >> 2, s = lin & 3, q = s ^ ((r >> 1) & 3);
      int ka = kn + q * 8;
      const unsigned short* ap = (ka < 256) ? &A[(size_t)(m0 + r) * CC + ka]
                                            : &A2[(size_t)(m0 + r) * CC + ka - 256];
      gl_lds16(ap, &As[lin * 8]);
      gl_lds16(&Bt[(size_t)(n0 + r) * K + kn + q * 8], &Bs[lin * 8]);
    }
    __syncthreads();
    bf16x8_t af[4], bf[4];
#pragma unroll
    for (int m = 0; m < 4; m++) {
      int r = wr * 64 + m * 16 + lr;
      int s = lq ^ ((r >> 1) & 3);
      af[m] = *(const bf16x8_t*)&As[r * 32 + s * 8];
    }
#pragma unroll
    for (int n = 0; n < 4; n++) {
      int r = wc * 64 + n * 16 + lr;
      int s = lq ^ ((r >> 1) & 3);
      bf[n] = *(const bf16x8_t*)&Bs[r * 32 + s * 8];
    }
#pragma unroll
    for (int m = 0; m < 4; m++)
#pragma unroll
      for (int n = 0; n < 4; n++)
        acc[m][n] = __builtin_amdgcn_mfma_f32_16x16x32_bf16(af[m], bf[n], acc[m][n], 0, 0, 0);
    __syncthreads();
  }

#pragma unroll
  for (int m = 0; m < 4; m++)
#pragma unroll
    for (int n = 0; n < 4; n++)
#pragma unroll
      for (int j = 0; j < 4; j++) {
        int row = m0 + wr * 64 + m * 16 + lq * 4 + j;
        int col = n0 + wc * 64 + n * 16 + lr;
        float x = acc[m][n][j];
        x = 0.5f * x * (1.0f + erff(x * 0.70710678118654752f));
        Out[(size_t)row * strideO + col] = f2bf(x);
      }
}

// ---------------------------------------------------------------------------
// attn2: per wave = one token (unchanged; validated rounds 6-9).
// ---------------------------------------------------------------------------
__global__ __launch_bounds__(256) void attn2_kernel(const unsigned short* __restrict__ QKc,
                                                    const float* __restrict__ target,
                                                    const float* __restrict__ wts,
                                                    const float* __restrict__ conf,
                                                    unsigned short* __restrict__ TC) {
  __shared__ __align__(16) unsigned short Ts[4][16 * 256];
  __shared__ float awL[4][PP][HH];
  const int tid = threadIdx.x;
  const int w = tid >> 6, l = tid & 63;
  const int t = blockIdx.x * 4 + w;
  const float* trow = target + (size_t)t * PP * CC;
  char* tsb = (char*)&Ts[w][0];

  {
    const int p = l >> 2;
#pragma unroll
    for (int i = 0; i < 8; i++) {
      int s = (l & 3) + i * 4;
      const float* gp = &trow[p * CC + s * 8];
      float4 v0 = *(const float4*)gp;
      float4 v1 = *(const float4*)(gp + 4);
      ushort4 u0 = make_ushort4(f2bf(v0.x), f2bf(v0.y), f2bf(v0.z), f2bf(v0.w));
      ushort4 u1 = make_ushort4(f2bf(v1.x), f2bf(v1.y), f2bf(v1.z), f2bf(v1.w));
      uint4 pk;
      pk.x = (unsigned)u0.x | ((unsigned)u0.y << 16);
      pk.y = (unsigned)u0.z | ((unsigned)u0.w << 16);
      pk.z = (unsigned)u1.x | ((unsigned)u1.y << 16);
      pk.w = (unsigned)u1.z | ((unsigned)u1.w << 16);
      *(uint4*)(tsb + p * 512 + ((s ^ (p & 7)) << 4)) = pk;
    }
  }

  f32x4_t sc4 = (f32x4_t){0.f, 0.f, 0.f, 0.f};
  {
    const int lr = l & 15, lq = l >> 4;
    const unsigned short* qkrow = QKc + (size_t)t * 2048 + (size_t)(lr & 7) * 256;
#pragma unroll
    for (int es = 0; es < 8; es++) {
      int slot = es * 4 + lq;
      bf16x8_t aF = *(const bf16x8_t*)(tsb + lr * 512 + ((slot ^ (lr & 7)) << 4));
      bf16x8_t bF = *(const bf16x8_t*)&qkrow[es * 32 + lq * 8];
      sc4 = __builtin_amdgcn_mfma_f32_16x16x32_bf16(aF, bF, sc4, 0, 0, 0);
    }
  }

  {
    const int g = l >> 4;
    const float rsD = 0.17677669529663687f;
    float sc[4], cf[4];
#pragma unroll
    for (int j = 0; j < 4; j++) {
      int p = g * 4 + j;
      sc[j] = sc4[j] * wts[(size_t)t * PP + p] * rsD;
      cf[j] = conf[(size_t)t * PP + p];
    }
    float mx = fmaxf(fmaxf(sc[0], sc[1]), fmaxf(sc[2], sc[3]));
    mx = fmaxf(mx, __shfl_xor(mx, 16, 64));
    mx = fmaxf(mx, __shfl_xor(mx, 32, 64));
    float ex[4], sm = 0.f;
#pragma unroll
    for (int j = 0; j < 4; j++) { ex[j] = expf(sc[j] - mx); sm += ex[j]; }
    sm += __shfl_xor(sm, 16, 64);
    sm += __shfl_xor(sm, 32, 64);
    float inv = 1.f / sm;
    if ((l & 15) < 8) {
#pragma unroll
      for (int j = 0; j < 4; j++) awL[w][g * 4 + j][l & 15] = ex[j] * inv * cf[j];
    }
  }

  float tc[HH][4];
#pragma unroll
  for (int h = 0; h < HH; h++)
#pragma unroll
    for (int j = 0; j < 4; j++) tc[h][j] = 0.f;
#pragma unroll
  for (int p = 0; p < PP; p++) {
    uint2 tv = *(const uint2*)(tsb + p * 512 + (((l >> 1) ^ (p & 7)) << 4) + (l & 1) * 8);
    float te0 = bf2f((unsigned short)(tv.x & 0xffff));
    float te1 = bf2f((unsigned short)(tv.x >> 16));
    float te2 = bf2f((unsigned short)(tv.y & 0xffff));
    float te3 = bf2f((unsigned short)(tv.y >> 16));
#pragma unroll
    for (int h = 0; h < HH; h++) {
      float a = awL[w][p][h];
      tc[h][0] += a * te0; tc[h][1] += a * te1;
      tc[h][2] += a * te2; tc[h][3] += a * te3;
    }
  }
  size_t tcb = (size_t)t * 2048;
#pragma unroll
  for (int h = 0; h < HH; h++) {
    ushort4 o = make_ushort4(f2bf(tc[h][0]), f2bf(tc[h][1]), f2bf(tc[h][2]), f2bf(tc[h][3]));
    *(ushort4*)&TC[tcb + h * 256 + 4 * l] = o;
  }
}

// ---------------------------------------------------------------------------
// nwide GEMM (BM=32, BN=256, K=2048), BK=64 single-buffer: 16 MFMA per
// barrier pair, 32 K-steps. 8-slot XOR swizzle s^(r&7).
// EPI: 0 = LN -> bf16; 1 = LN + residual -> f32.
// ---------------------------------------------------------------------------
template<int EPI>
__global__ __launch_bounds__(256) void nwide_gemm_kernel(
    const unsigned short* __restrict__ A, const unsigned short* __restrict__ Bt,
    unsigned short* __restrict__ OutB, float* __restrict__ OutF,
    const float* __restrict__ gam, const float* __restrict__ bet,
    const float* __restrict__ res) {
  __shared__ __align__(16) unsigned short As[32 * 64];    // 4 KB
  __shared__ __align__(16) unsigned short Bs[256 * 64];   // 32 KB
  __shared__ float redS[32][5], redQ[32][5];
  const int tid = threadIdx.x;
  const int wc = tid >> 6, l = tid & 63;
  const int lr = l & 15, lq = l >> 4;
  const int m0 = blockIdx.x * 32;
  const int K = 2048;

  f32x4_t acc[2][4];
#pragma unroll
  for (int m = 0; m < 2; m++)
#pragma unroll
    for (int n = 0; n < 4; n++) acc[m][n] = (f32x4_t){0.f, 0.f, 0.f, 0.f};

  const int rS = tid >> 3, sS = tid & 7, qS = sS ^ (rS & 7);

  for (int st = 0; st < 32; st++) {
    int kn = st * 64;
    // A: 32 rows x 64 k = 256 x 16B chunks, one per thread
    gl_lds16(&A[(size_t)(m0 + rS) * K + kn + qS * 8], &As[tid * 8]);
    // B: 256 rows x 64 k = 2048 chunks, 8 per thread
#pragma unroll
    for (int it = 0; it < 8; it++) {
      int lin = it * 256 + tid, r = lin >> 3, s = lin & 7, q = s ^ (r & 7);
      gl_lds16(&Bt[(size_t)r * K + kn + q * 8], &Bs[lin * 8]);
    }
    __syncthreads();
#pragma unroll
    for (int kk = 0; kk < 2; kk++) {
      bf16x8_t af[2], bfr[4];
#pragma unroll
      for (int m = 0; m < 2; m++) {
        int r = m * 16 + lr;
        int slot = (kk * 4 + lq) ^ (r & 7);
        af[m] = *(const bf16x8_t*)&As[r * 64 + slot * 8];
      }
#pragma unroll
      for (int n = 0; n < 4; n++) {
        int r = wc * 64 + n * 16 + lr;
        int slot = (kk * 4 + lq) ^ (r & 7);
        bfr[n] = *(const bf16x8_t*)&Bs[r * 64 + slot * 8];
      }
#pragma unroll
      for (int m = 0; m < 2; m++)
#pragma unroll
        for (int n = 0; n < 4; n++)
          acc[m][n] = __builtin_amdgcn_mfma_f32_16x16x32_bf16(af[m], bfr[n], acc[m][n], 0, 0, 0);
    }
    __syncthreads();
  }

  // LN epilogue (block covers the full 256-col row)
  float s1[2][4], s2[2][4];
#pragma unroll
  for (int m = 0; m < 2; m++)
#pragma unroll
    for (int j = 0; j < 4; j++) {
      float a = 0.f, b = 0.f;
#pragma unroll
      for (int n = 0; n < 4; n++) { float x = acc[m][n][j]; a += x; b += x * x; }
      s1[m][j] = a; s2[m][j] = b;
    }
#pragma unroll
  for (int mask = 1; mask < 16; mask <<= 1)
#pragma unroll
    for (int m = 0; m < 2; m++)
#pragma unroll
      for (int j = 0; j < 4; j++) {
        s1[m][j] += __shfl_xor(s1[m][j], mask, 64);
        s2[m][j] += __shfl_xor(s2[m][j], mask, 64);
      }
  if (lr == 0) {
#pragma unroll
    for (int m = 0; m < 2; m++)
#pragma unroll
      for (int j = 0; j < 4; j++) {
        int rl = m * 16 + lq * 4 + j;
        redS[rl][wc] = s1[m][j];
        redQ[rl][wc] = s2[m][j];
      }
  }
  __syncthreads();
#pragma unroll
  for (int m = 0; m < 2; m++)
#pragma unroll
    for (int j = 0; j < 4; j++) {
      int rl = m * 16 + lq * 4 + j;
      float ts = redS[rl][0] + redS[rl][1] + redS[rl][2] + redS[rl][3];
      float tq = redQ[rl][0] + redQ[rl][1] + redQ[rl][2] + redQ[rl][3];
      float mu = ts * (1.f / 256.f);
      float var = tq * (1.f / 256.f) - mu * mu;
      float rs = rsqrtf(var + LN_EPS);
      size_t rowg = (size_t)(m0 + rl);
#pragma unroll
      for (int n = 0; n < 4; n++) {
        int col = wc * 64 + n * 16 + lr;
        float v = (acc[m][n][j] - mu) * rs * gam[col] + bet[col];
        if constexpr (EPI == 0) {
          OutB[rowg * CC + col] = f2bf(v);
        } else {
          OutF[rowg * CC + col] = res[rowg * CC + col] + v;
        }
      }
    }
}

extern "C" void kernel_launch(void* const* d_in, const int* in_sizes, int n_in,
                              void* d_out, int out_size, void* d_ws, size_t ws_size,
                              hipStream_t stream) {
  const float* source = (const float*)d_in[0];
  const float* target = (const float*)d_in[1];
  const float* weights = (const float*)d_in[2];
  const float* conf   = (const float*)d_in[3];
  const float* Wq = (const float*)d_in[4];
  const float* Wk = (const float*)d_in[5];
  const float* Wv = (const float*)d_in[6];
  const float* Wm = (const float*)d_in[7];
  const float* g1 = (const float*)d_in[8];
  const float* b1 = (const float*)d_in[9];
  const float* Wf1 = (const float*)d_in[10];
  const float* Wf2 = (const float*)d_in[11];
  const float* g2 = (const float*)d_in[12];
  const float* b2 = (const float*)d_in[13];
  float* out = (float*)d_out;

  unsigned short* SB   = (unsigned short*)d_ws;                 // [16384][256]
  unsigned short* MSGb = SB + (size_t)T_TOK * CC;               // [16384][256]
  unsigned short* Mt   = MSGb + (size_t)T_TOK * CC;             // [2048][256]
  unsigned short* WVMt = Mt + (size_t)2048 * 256;               // [256][2048]
  unsigned short* WF1t = WVMt + (size_t)256 * 2048;             // [2048][512]
  unsigned short* WF2t = WF1t + (size_t)2048 * 512;             // [256][2048]
  unsigned short* BIG1 = WF2t + (size_t)256 * 2048;             // QKc, later hid
  unsigned short* BIG2 = BIG1 + (size_t)T_TOK * 2048;           // TC
  unsigned short* QKc  = BIG1;
  unsigned short* hid  = BIG1;
  unsigned short* TC   = BIG2;

  // prep
  cvt_bf16_kernel<<<T_TOK * CC / 1024, 256, 0, stream>>>(source, SB);
  transpose_cvt_kernel<<<dim3(8, 32), 256, 0, stream>>>(Wf1, WF1t, 512, 2048);
  transpose_cvt_kernel<<<dim3(32, 4), 256, 0, stream>>>(Wf2, WF2t, 2048, 256);
  precM_kernel<<<16, 256, 0, stream>>>(Wq, Wk, Mt);
  precWVM_kernel<<<8, 256, 0, stream>>>(Wv, Wm, WVMt);

  // attention pipeline: QKc = SB @ Mt^T
  qk_gemm_kernel<<<dim3(T_TOK / 64, 8), 512, 0, stream>>>(SB, Mt, QKc, 256, 2048);
  attn2_kernel<<<T_TOK / 4, 256, 0, stream>>>(QKc, target, weights, conf, TC);
  // message = LN(TC @ WVMt^T)
  nwide_gemm_kernel<0><<<T_TOK / 32, 256, 0, stream>>>(
      TC, WVMt, MSGb, nullptr, g1, b1, nullptr);

  // FFN: hid = gelu([SB||MSG] @ W1t^T)  (128x128 tiles)
  gemm128_kernel<<<dim3(T_TOK / 128, 16), 256, 0, stream>>>(
      SB, MSGb, WF1t, hid, 512, 2048);
  // out = src + LN(hid @ W2t^T)
  nwide_gemm_kernel<1><<<T_TOK / 32, 256, 0, stream>>>(
      hid, WF2t, nullptr, out, g2, b2, source);
}

// Round 11
// 328.164 us; speedup vs baseline: 1.1222x; 1.0768x over previous
//
#include <hip/hip_runtime.h>
#include <hip/hip_bf16.h>
#include <math.h>

#define T_TOK 16384
#define CC 256
#define PP 16
#define HH 8
#define DD 32
#define LN_EPS 1e-5f

typedef __attribute__((ext_vector_type(8))) short bf16x8_t;
typedef __attribute__((ext_vector_type(4))) float f32x4_t;

__device__ __forceinline__ unsigned short f2bf(float x) {
  __hip_bfloat16 h = __float2bfloat16(x);
  return *reinterpret_cast<unsigned short*>(&h);
}
__device__ __forceinline__ float bf2f(unsigned short u) {
  union { unsigned int i; float f; } v; v.i = ((unsigned int)u) << 16; return v.f;
}
// async global->LDS, 16B per lane; LDS dest must be wave-uniform base + lane*16
__device__ __forceinline__ void gl_lds16(const unsigned short* g, unsigned short* l) {
  __builtin_amdgcn_global_load_lds(
      (const __attribute__((address_space(1))) unsigned int*)g,
      (__attribute__((address_space(3))) unsigned int*)l, 16, 0, 0);
}

// ---------------------------------------------------------------------------
// Prep kernels
// ---------------------------------------------------------------------------
__global__ __launch_bounds__(256) void cvt_bf16_kernel(const float* __restrict__ src,
                                                       unsigned short* __restrict__ dst) {
  int i = (blockIdx.x * 256 + threadIdx.x) * 4;
  float4 v = *(const float4*)&src[i];
  ushort4 o = make_ushort4(f2bf(v.x), f2bf(v.y), f2bf(v.z), f2bf(v.w));
  *(ushort4*)&dst[i] = o;
}

__global__ __launch_bounds__(256) void transpose_cvt_kernel(const float* __restrict__ src,
                                                            unsigned short* __restrict__ dst,
                                                            int K, int N) {
  __shared__ float tile[64][65];
  int k0 = blockIdx.x * 64, n0 = blockIdx.y * 64;
  int tid = threadIdx.x;
#pragma unroll
  for (int i = 0; i < 16; i++) {
    int lin = i * 256 + tid, r = lin >> 6, c = lin & 63;
    tile[r][c] = src[(size_t)(k0 + r) * N + n0 + c];
  }
  __syncthreads();
#pragma unroll
  for (int i = 0; i < 16; i++) {
    int lin = i * 256 + tid, n = lin >> 6, k = lin & 63;
    dst[(size_t)(n0 + n) * K + k0 + k] = f2bf(tile[k][n]);
  }
}

// Mt[(h*256+e)][c] = bf16( sum_d Wq[c][h*32+d] * Wk[e][h*32+d] )
__global__ __launch_bounds__(256) void precM_kernel(const float* __restrict__ Wq,
                                                    const float* __restrict__ Wk,
                                                    unsigned short* __restrict__ Mt) {
  __shared__ float wqS[256][33];
  __shared__ float wkS[128][33];
  const int tid = threadIdx.x;
  const int h = blockIdx.x >> 1, eh = blockIdx.x & 1;
#pragma unroll
  for (int it = 0; it < 32; it++) {
    int lin = it * 256 + tid, r = lin >> 5, d = lin & 31;
    wqS[r][d] = Wq[(size_t)r * CC + h * DD + d];
  }
#pragma unroll
  for (int it = 0; it < 16; it++) {
    int lin = it * 256 + tid, r = lin >> 5, d = lin & 31;
    wkS[r][d] = Wk[(size_t)(eh * 128 + r) * CC + h * DD + d];
  }
  __syncthreads();
  const int w = tid >> 6, l = tid & 63;
  for (int ei = 0; ei < 32; ei++) {
    int e = w * 32 + ei;
    float o[4] = {0.f, 0.f, 0.f, 0.f};
#pragma unroll
    for (int d = 0; d < 32; d++) {
      float kv = wkS[e][d];
      o[0] += kv * wqS[l][d];
      o[1] += kv * wqS[l + 64][d];
      o[2] += kv * wqS[l + 128][d];
      o[3] += kv * wqS[l + 192][d];
    }
    size_t rowb = (size_t)(h * 256 + eh * 128 + e) * CC;
    Mt[rowb + l] = f2bf(o[0]);
    Mt[rowb + l + 64] = f2bf(o[1]);
    Mt[rowb + l + 128] = f2bf(o[2]);
    Mt[rowb + l + 192] = f2bf(o[3]);
  }
}

// WVMt[c][h*256+e] = bf16( sum_d Wv[e][h*32+d] * Wm[h*32+d][c] ); grid = 8 (h)
__global__ __launch_bounds__(256) void precWVM_kernel(const float* __restrict__ Wv,
                                                      const float* __restrict__ Wm,
                                                      unsigned short* __restrict__ WVMt) {
  __shared__ float WvS[256][33];
  __shared__ float WmS[32][257];
  const int h = blockIdx.x;
  const int tid = threadIdx.x;
#pragma unroll
  for (int it = 0; it < 32; it++) {
    int lin = it * 256 + tid, e = lin >> 5, d = lin & 31;
    WvS[e][d] = Wv[(size_t)e * CC + h * DD + d];
  }
#pragma unroll
  for (int it = 0; it < 32; it++) {
    int lin = it * 256 + tid, d = lin >> 8, c = lin & 255;
    WmS[d][c] = Wm[(size_t)(h * DD + d) * CC + c];
  }
  __syncthreads();
  float wm[32];
#pragma unroll
  for (int d = 0; d < 32; d++) wm[d] = WmS[d][tid];
  for (int e = 0; e < 256; e++) {
    float acc = 0.f;
#pragma unroll
    for (int d = 0; d < 32; d++) acc += WvS[e][d] * wm[d];
    WVMt[(size_t)tid * 2048 + h * 256 + e] = f2bf(acc);
  }
}

// ---------------------------------------------------------------------------
// QK GEMM: Out = A[M,256] @ Bt^T, BM=64 BN=256 BK=64, 512 thr, single-buffer.
// 16 MFMA per barrier pair; 8-slot XOR swizzle s^(r&7).
// ---------------------------------------------------------------------------
__global__ __launch_bounds__(512) void qk_gemm_kernel(
    const unsigned short* __restrict__ A, const unsigned short* __restrict__ Bt,
    unsigned short* __restrict__ Out, int K, int strideO) {
  __shared__ __align__(16) unsigned short As[64 * 64];    // 8 KB
  __shared__ __align__(16) unsigned short Bs[256 * 64];   // 32 KB
  const int tid = threadIdx.x;
  const int wv = tid >> 6, l = tid & 63;
  const int wr = wv >> 2, wc = wv & 3;
  const int lr = l & 15, lq = l >> 4;
  const int m0 = blockIdx.x * 64;
  const int n0 = blockIdx.y * 256;
  const int nsteps = K >> 6;

  f32x4_t acc[2][4];
#pragma unroll
  for (int m = 0; m < 2; m++)
#pragma unroll
    for (int n = 0; n < 4; n++) acc[m][n] = (f32x4_t){0.f, 0.f, 0.f, 0.f};

  const int rS = tid >> 3, sS = tid & 7, qS = sS ^ (rS & 7);

  for (int st = 0; st < nsteps; st++) {
    int kn = st * 64;
    // A: 64 rows x 64 k = 512 x 16B chunks, one per thread
    gl_lds16(&A[(size_t)(m0 + rS) * K + kn + qS * 8], &As[tid * 8]);
    // B: 256 rows x 64 k = 2048 chunks, 4 per thread
#pragma unroll
    for (int it = 0; it < 4; it++) {
      int lin = it * 512 + tid, r = lin >> 3, s = lin & 7, q = s ^ (r & 7);
      gl_lds16(&Bt[(size_t)(n0 + r) * K + kn + q * 8], &Bs[lin * 8]);
    }
    __syncthreads();
#pragma unroll
    for (int kk = 0; kk < 2; kk++) {
      bf16x8_t af[2], bfr[4];
#pragma unroll
      for (int m = 0; m < 2; m++) {
        int r = wr * 32 + m * 16 + lr;
        int slot = (kk * 4 + lq) ^ (r & 7);
        af[m] = *(const bf16x8_t*)&As[r * 64 + slot * 8];
      }
#pragma unroll
      for (int n = 0; n < 4; n++) {
        int r = wc * 64 + n * 16 + lr;
        int slot = (kk * 4 + lq) ^ (r & 7);
        bfr[n] = *(const bf16x8_t*)&Bs[r * 64 + slot * 8];
      }
#pragma unroll
      for (int m = 0; m < 2; m++)
#pragma unroll
        for (int n = 0; n < 4; n++)
          acc[m][n] = __builtin_amdgcn_mfma_f32_16x16x32_bf16(af[m], bfr[n], acc[m][n], 0, 0, 0);
    }
    __syncthreads();
  }

#pragma unroll
  for (int m = 0; m < 2; m++)
#pragma unroll
    for (int n = 0; n < 4; n++)
#pragma unroll
      for (int j = 0; j < 4; j++) {
        int rl = wr * 32 + m * 16 + lq * 4 + j;
        int col = n0 + wc * 64 + n * 16 + lr;
        Out[(size_t)(m0 + rl) * strideO + col] = f2bf(acc[m][n][j]);
      }
}

// ---------------------------------------------------------------------------
// gemm1: hid = gelu([A||A2][M,512] @ Bt^T). BM=BN=128, BK=64, 256 thr,
// single-buffer; 32 MFMA per barrier pair.
// ---------------------------------------------------------------------------
__global__ __launch_bounds__(256) void gemm128_kernel(
    const unsigned short* __restrict__ A, const unsigned short* __restrict__ A2,
    const unsigned short* __restrict__ Bt, unsigned short* __restrict__ Out,
    int K, int strideO) {
  __shared__ __align__(16) unsigned short As[128 * 64];   // 16 KB
  __shared__ __align__(16) unsigned short Bs[128 * 64];   // 16 KB
  const int tid = threadIdx.x;
  const int wv = tid >> 6, l = tid & 63;
  const int wr = wv >> 1, wc = wv & 1;
  const int lr = l & 15, lq = l >> 4;
  const int m0 = blockIdx.x * 128;
  const int n0 = blockIdx.y * 128;
  const int nsteps = K >> 6;

  f32x4_t acc[4][4];
#pragma unroll
  for (int m = 0; m < 4; m++)
#pragma unroll
    for (int n = 0; n < 4; n++) acc[m][n] = (f32x4_t){0.f, 0.f, 0.f, 0.f};

  for (int st = 0; st < nsteps; st++) {
    int kn = st * 64;
    // A: 128 rows x 64 k = 1024 chunks, 4 per thread (concat over k)
#pragma unroll
    for (int it = 0; it < 4; it++) {
      int lin = it * 256 + tid, r = lin >> 3, s = lin & 7, q = s ^ (r & 7);
      int ka = kn + q * 8;
      const unsigned short* ap = (ka < 256) ? &A[(size_t)(m0 + r) * CC + ka]
                                            : &A2[(size_t)(m0 + r) * CC + ka - 256];
      gl_lds16(ap, &As[lin * 8]);
      gl_lds16(&Bt[(size_t)(n0 + r) * K + kn + q * 8], &Bs[lin * 8]);
    }
    __syncthreads();
#pragma unroll
    for (int kk = 0; kk < 2; kk++) {
      bf16x8_t af[4], bf[4];
#pragma unroll
      for (int m = 0; m < 4; m++) {
        int r = wr * 64 + m * 16 + lr;
        int slot = (kk * 4 + lq) ^ (r & 7);
        af[m] = *(const bf16x8_t*)&As[r * 64 + slot * 8];
      }
#pragma unroll
      for (int n = 0; n < 4; n++) {
        int r = wc * 64 + n * 16 + lr;
        int slot = (kk * 4 + lq) ^ (r & 7);
        bf[n] = *(const bf16x8_t*)&Bs[r * 64 + slot * 8];
      }
#pragma unroll
      for (int m = 0; m < 4; m++)
#pragma unroll
        for (int n = 0; n < 4; n++)
          acc[m][n] = __builtin_amdgcn_mfma_f32_16x16x32_bf16(af[m], bf[n], acc[m][n], 0, 0, 0);
    }
    __syncthreads();
  }

#pragma unroll
  for (int m = 0; m < 4; m++)
#pragma unroll
    for (int n = 0; n < 4; n++)
#pragma unroll
      for (int j = 0; j < 4; j++) {
        int row = m0 + wr * 64 + m * 16 + lq * 4 + j;
        int col = n0 + wc * 64 + n * 16 + lr;
        float x = acc[m][n][j];
        x = 0.5f * x * (1.0f + erff(x * 0.70710678118654752f));
        Out[(size_t)row * strideO + col] = f2bf(x);
      }
}

// ---------------------------------------------------------------------------
// attn2: per wave = one token (unchanged; validated rounds 6-10).
// ---------------------------------------------------------------------------
__global__ __launch_bounds__(256) void attn2_kernel(const unsigned short* __restrict__ QKc,
                                                    const float* __restrict__ target,
                                                    const float* __restrict__ wts,
                                                    const float* __restrict__ conf,
                                                    unsigned short* __restrict__ TC) {
  __shared__ __align__(16) unsigned short Ts[4][16 * 256];
  __shared__ float awL[4][PP][HH];
  const int tid = threadIdx.x;
  const int w = tid >> 6, l = tid & 63;
  const int t = blockIdx.x * 4 + w;
  const float* trow = target + (size_t)t * PP * CC;
  char* tsb = (char*)&Ts[w][0];

  {
    const int p = l >> 2;
#pragma unroll
    for (int i = 0; i < 8; i++) {
      int s = (l & 3) + i * 4;
      const float* gp = &trow[p * CC + s * 8];
      float4 v0 = *(const float4*)gp;
      float4 v1 = *(const float4*)(gp + 4);
      ushort4 u0 = make_ushort4(f2bf(v0.x), f2bf(v0.y), f2bf(v0.z), f2bf(v0.w));
      ushort4 u1 = make_ushort4(f2bf(v1.x), f2bf(v1.y), f2bf(v1.z), f2bf(v1.w));
      uint4 pk;
      pk.x = (unsigned)u0.x | ((unsigned)u0.y << 16);
      pk.y = (unsigned)u0.z | ((unsigned)u0.w << 16);
      pk.z = (unsigned)u1.x | ((unsigned)u1.y << 16);
      pk.w = (unsigned)u1.z | ((unsigned)u1.w << 16);
      *(uint4*)(tsb + p * 512 + ((s ^ (p & 7)) << 4)) = pk;
    }
  }

  f32x4_t sc4 = (f32x4_t){0.f, 0.f, 0.f, 0.f};
  {
    const int lr = l & 15, lq = l >> 4;
    const unsigned short* qkrow = QKc + (size_t)t * 2048 + (size_t)(lr & 7) * 256;
#pragma unroll
    for (int es = 0; es < 8; es++) {
      int slot = es * 4 + lq;
      bf16x8_t aF = *(const bf16x8_t*)(tsb + lr * 512 + ((slot ^ (lr & 7)) << 4));
      bf16x8_t bF = *(const bf16x8_t*)&qkrow[es * 32 + lq * 8];
      sc4 = __builtin_amdgcn_mfma_f32_16x16x32_bf16(aF, bF, sc4, 0, 0, 0);
    }
  }

  {
    const int g = l >> 4;
    const float rsD = 0.17677669529663687f;
    float sc[4], cf[4];
#pragma unroll
    for (int j = 0; j < 4; j++) {
      int p = g * 4 + j;
      sc[j] = sc4[j] * wts[(size_t)t * PP + p] * rsD;
      cf[j] = conf[(size_t)t * PP + p];
    }
    float mx = fmaxf(fmaxf(sc[0], sc[1]), fmaxf(sc[2], sc[3]));
    mx = fmaxf(mx, __shfl_xor(mx, 16, 64));
    mx = fmaxf(mx, __shfl_xor(mx, 32, 64));
    float ex[4], sm = 0.f;
#pragma unroll
    for (int j = 0; j < 4; j++) { ex[j] = expf(sc[j] - mx); sm += ex[j]; }
    sm += __shfl_xor(sm, 16, 64);
    sm += __shfl_xor(sm, 32, 64);
    float inv = 1.f / sm;
    if ((l & 15) < 8) {
#pragma unroll
      for (int j = 0; j < 4; j++) awL[w][g * 4 + j][l & 15] = ex[j] * inv * cf[j];
    }
  }

  float tc[HH][4];
#pragma unroll
  for (int h = 0; h < HH; h++)
#pragma unroll
    for (int j = 0; j < 4; j++) tc[h][j] = 0.f;
#pragma unroll
  for (int p = 0; p < PP; p++) {
    uint2 tv = *(const uint2*)(tsb + p * 512 + (((l >> 1) ^ (p & 7)) << 4) + (l & 1) * 8);
    float te0 = bf2f((unsigned short)(tv.x & 0xffff));
    float te1 = bf2f((unsigned short)(tv.x >> 16));
    float te2 = bf2f((unsigned short)(tv.y & 0xffff));
    float te3 = bf2f((unsigned short)(tv.y >> 16));
#pragma unroll
    for (int h = 0; h < HH; h++) {
      float a = awL[w][p][h];
      tc[h][0] += a * te0; tc[h][1] += a * te1;
      tc[h][2] += a * te2; tc[h][3] += a * te3;
    }
  }
  size_t tcb = (size_t)t * 2048;
#pragma unroll
  for (int h = 0; h < HH; h++) {
    ushort4 o = make_ushort4(f2bf(tc[h][0]), f2bf(tc[h][1]), f2bf(tc[h][2]), f2bf(tc[h][3]));
    *(ushort4*)&TC[tcb + h * 256 + 4 * l] = o;
  }
}

// ---------------------------------------------------------------------------
// nwide GEMM (BM=32, BN=256, K=2048), BK=64 single-buffer (validated r10).
// EPI: 0 = LN -> bf16; 1 = LN + residual -> f32.
// ---------------------------------------------------------------------------
template<int EPI>
__global__ __launch_bounds__(256) void nwide_gemm_kernel(
    const unsigned short* __restrict__ A, const unsigned short* __restrict__ Bt,
    unsigned short* __restrict__ OutB, float* __restrict__ OutF,
    const float* __restrict__ gam, const float* __restrict__ bet,
    const float* __restrict__ res) {
  __shared__ __align__(16) unsigned short As[32 * 64];    // 4 KB
  __shared__ __align__(16) unsigned short Bs[256 * 64];   // 32 KB
  __shared__ float redS[32][5], redQ[32][5];
  const int tid = threadIdx.x;
  const int wc = tid >> 6, l = tid & 63;
  const int lr = l & 15, lq = l >> 4;
  const int m0 = blockIdx.x * 32;
  const int K = 2048;

  f32x4_t acc[2][4];
#pragma unroll
  for (int m = 0; m < 2; m++)
#pragma unroll
    for (int n = 0; n < 4; n++) acc[m][n] = (f32x4_t){0.f, 0.f, 0.f, 0.f};

  const int rS = tid >> 3, sS = tid & 7, qS = sS ^ (rS & 7);

  for (int st = 0; st < 32; st++) {
    int kn = st * 64;
    gl_lds16(&A[(size_t)(m0 + rS) * K + kn + qS * 8], &As[tid * 8]);
#pragma unroll
    for (int it = 0; it < 8; it++) {
      int lin = it * 256 + tid, r = lin >> 3, s = lin & 7, q = s ^ (r & 7);
      gl_lds16(&Bt[(size_t)r * K + kn + q * 8], &Bs[lin * 8]);
    }
    __syncthreads();
#pragma unroll
    for (int kk = 0; kk < 2; kk++) {
      bf16x8_t af[2], bfr[4];
#pragma unroll
      for (int m = 0; m < 2; m++) {
        int r = m * 16 + lr;
        int slot = (kk * 4 + lq) ^ (r & 7);
        af[m] = *(const bf16x8_t*)&As[r * 64 + slot * 8];
      }
#pragma unroll
      for (int n = 0; n < 4; n++) {
        int r = wc * 64 + n * 16 + lr;
        int slot = (kk * 4 + lq) ^ (r & 7);
        bfr[n] = *(const bf16x8_t*)&Bs[r * 64 + slot * 8];
      }
#pragma unroll
      for (int m = 0; m < 2; m++)
#pragma unroll
        for (int n = 0; n < 4; n++)
          acc[m][n] = __builtin_amdgcn_mfma_f32_16x16x32_bf16(af[m], bfr[n], acc[m][n], 0, 0, 0);
    }
    __syncthreads();
  }

  // LN epilogue (block covers the full 256-col row)
  float s1[2][4], s2[2][4];
#pragma unroll
  for (int m = 0; m < 2; m++)
#pragma unroll
    for (int j = 0; j < 4; j++) {
      float a = 0.f, b = 0.f;
#pragma unroll
      for (int n = 0; n < 4; n++) { float x = acc[m][n][j]; a += x; b += x * x; }
      s1[m][j] = a; s2[m][j] = b;
    }
#pragma unroll
  for (int mask = 1; mask < 16; mask <<= 1)
#pragma unroll
    for (int m = 0; m < 2; m++)
#pragma unroll
      for (int j = 0; j < 4; j++) {
        s1[m][j] += __shfl_xor(s1[m][j], mask, 64);
        s2[m][j] += __shfl_xor(s2[m][j], mask, 64);
      }
  if (lr == 0) {
#pragma unroll
    for (int m = 0; m < 2; m++)
#pragma unroll
      for (int j = 0; j < 4; j++) {
        int rl = m * 16 + lq * 4 + j;
        redS[rl][wc] = s1[m][j];
        redQ[rl][wc] = s2[m][j];
      }
  }
  __syncthreads();
#pragma unroll
  for (int m = 0; m < 2; m++)
#pragma unroll
    for (int j = 0; j < 4; j++) {
      int rl = m * 16 + lq * 4 + j;
      float ts = redS[rl][0] + redS[rl][1] + redS[rl][2] + redS[rl][3];
      float tq = redQ[rl][0] + redQ[rl][1] + redQ[rl][2] + redQ[rl][3];
      float mu = ts * (1.f / 256.f);
      float var = tq * (1.f / 256.f) - mu * mu;
      float rs = rsqrtf(var + LN_EPS);
      size_t rowg = (size_t)(m0 + rl);
#pragma unroll
      for (int n = 0; n < 4; n++) {
        int col = wc * 64 + n * 16 + lr;
        float v = (acc[m][n][j] - mu) * rs * gam[col] + bet[col];
        if constexpr (EPI == 0) {
          OutB[rowg * CC + col] = f2bf(v);
        } else {
          OutF[rowg * CC + col] = res[rowg * CC + col] + v;
        }
      }
    }
}

extern "C" void kernel_launch(void* const* d_in, const int* in_sizes, int n_in,
                              void* d_out, int out_size, void* d_ws, size_t ws_size,
                              hipStream_t stream) {
  const float* source = (const float*)d_in[0];
  const float* target = (const float*)d_in[1];
  const float* weights = (const float*)d_in[2];
  const float* conf   = (const float*)d_in[3];
  const float* Wq = (const float*)d_in[4];
  const float* Wk = (const float*)d_in[5];
  const float* Wv = (const float*)d_in[6];
  const float* Wm = (const float*)d_in[7];
  const float* g1 = (const float*)d_in[8];
  const float* b1 = (const float*)d_in[9];
  const float* Wf1 = (const float*)d_in[10];
  const float* Wf2 = (const float*)d_in[11];
  const float* g2 = (const float*)d_in[12];
  const float* b2 = (const float*)d_in[13];
  float* out = (float*)d_out;

  unsigned short* SB   = (unsigned short*)d_ws;                 // [16384][256]
  unsigned short* MSGb = SB + (size_t)T_TOK * CC;               // [16384][256]
  unsigned short* Mt   = MSGb + (size_t)T_TOK * CC;             // [2048][256]
  unsigned short* WVMt = Mt + (size_t)2048 * 256;               // [256][2048]
  unsigned short* WF1t = WVMt + (size_t)256 * 2048;             // [2048][512]
  unsigned short* WF2t = WF1t + (size_t)2048 * 512;             // [256][2048]
  unsigned short* BIG1 = WF2t + (size_t)256 * 2048;             // QKc, later hid
  unsigned short* BIG2 = BIG1 + (size_t)T_TOK * 2048;           // TC
  unsigned short* QKc  = BIG1;
  unsigned short* hid  = BIG1;
  unsigned short* TC   = BIG2;

  // prep
  cvt_bf16_kernel<<<T_TOK * CC / 1024, 256, 0, stream>>>(source, SB);
  transpose_cvt_kernel<<<dim3(8, 32), 256, 0, stream>>>(Wf1, WF1t, 512, 2048);
  transpose_cvt_kernel<<<dim3(32, 4), 256, 0, stream>>>(Wf2, WF2t, 2048, 256);
  precM_kernel<<<16, 256, 0, stream>>>(Wq, Wk, Mt);
  precWVM_kernel<<<8, 256, 0, stream>>>(Wv, Wm, WVMt);

  // attention pipeline: QKc = SB @ Mt^T
  qk_gemm_kernel<<<dim3(T_TOK / 64, 8), 512, 0, stream>>>(SB, Mt, QKc, 256, 2048);
  attn2_kernel<<<T_TOK / 4, 256, 0, stream>>>(QKc, target, weights, conf, TC);
  // message = LN(TC @ WVMt^T)
  nwide_gemm_kernel<0><<<T_TOK / 32, 256, 0, stream>>>(
      TC, WVMt, MSGb, nullptr, g1, b1, nullptr);

  // FFN: hid = gelu([SB||MSG] @ W1t^T)
  gemm128_kernel<<<dim3(T_TOK / 128, 16), 256, 0, stream>>>(
      SB, MSGb, WF1t, hid, 512, 2048);
  // out = src + LN(hid @ W2t^T)
  nwide_gemm_kernel<1><<<T_TOK / 32, 256, 0, stream>>>(
      hid, WF2t, nullptr, out, g2, b2, source);
}

// Round 12
// 302.711 us; speedup vs baseline: 1.2166x; 1.0841x over previous
//
#include <hip/hip_runtime.h>
#include <hip/hip_bf16.h>
#include <math.h>

#define T_TOK 16384
#define CC 256
#define PP 16
#define HH 8
#define DD 32
#define LN_EPS 1e-5f

typedef __attribute__((ext_vector_type(8))) short bf16x8_t;
typedef __attribute__((ext_vector_type(4))) float f32x4_t;

__device__ __forceinline__ unsigned short f2bf(float x) {
  __hip_bfloat16 h = __float2bfloat16(x);
  return *reinterpret_cast<unsigned short*>(&h);
}
__device__ __forceinline__ float bf2f(unsigned short u) {
  union { unsigned int i; float f; } v; v.i = ((unsigned int)u) << 16; return v.f;
}
// async global->LDS, 16B per lane; LDS dest must be wave-uniform base + lane*16
__device__ __forceinline__ void gl_lds16(const unsigned short* g, unsigned short* l) {
  __builtin_amdgcn_global_load_lds(
      (const __attribute__((address_space(1))) unsigned int*)g,
      (__attribute__((address_space(3))) unsigned int*)l, 16, 0, 0);
}

// ---------------------------------------------------------------------------
// cvt: f32 -> bf16 rowmajor copy (source -> SB)
// ---------------------------------------------------------------------------
__global__ __launch_bounds__(256) void cvt_bf16_kernel(const float* __restrict__ src,
                                                       unsigned short* __restrict__ dst) {
  int i = (blockIdx.x * 256 + threadIdx.x) * 4;
  float4 v = *(const float4*)&src[i];
  ushort4 o = make_ushort4(f2bf(v.x), f2bf(v.y), f2bf(v.z), f2bf(v.w));
  *(ushort4*)&dst[i] = o;
}

// ---------------------------------------------------------------------------
// Fused small preps: blocks [0,256) transpose Wf1; [256,384) transpose Wf2;
// [384,400) precM (Wq.Wk^T head blocks); [400,408) precWVM (Wv.Wm fold).
// All branches are block-uniform so __syncthreads stays legal.
// ---------------------------------------------------------------------------
__global__ __launch_bounds__(256) void prep_small_kernel(
    const float* __restrict__ Wf1, const float* __restrict__ Wf2,
    const float* __restrict__ Wq, const float* __restrict__ Wk,
    const float* __restrict__ Wv, const float* __restrict__ Wm,
    unsigned short* __restrict__ WF1t, unsigned short* __restrict__ WF2t,
    unsigned short* __restrict__ Mt, unsigned short* __restrict__ WVMt) {
  __shared__ __align__(16) char smem[66688];
  const int b = blockIdx.x;
  const int tid = threadIdx.x;

  if (b < 384) {
    // ---- transpose + cvt: dst[n][k] = bf16(src[k][n]) ----
    const float* src; unsigned short* dst; int K, N, k0, n0;
    if (b < 256) { src = Wf1; dst = WF1t; K = 512;  N = 2048; k0 = (b & 7) * 64;  n0 = (b >> 3) * 64; }
    else { int bb = b - 256; src = Wf2; dst = WF2t; K = 2048; N = 256;  k0 = (bb & 31) * 64; n0 = (bb >> 5) * 64; }
    float (*tile)[65] = (float (*)[65])smem;
#pragma unroll
    for (int i = 0; i < 16; i++) {
      int lin = i * 256 + tid, r = lin >> 6, c = lin & 63;
      tile[r][c] = src[(size_t)(k0 + r) * N + n0 + c];
    }
    __syncthreads();
#pragma unroll
    for (int i = 0; i < 16; i++) {
      int lin = i * 256 + tid, n = lin >> 6, k = lin & 63;
      dst[(size_t)(n0 + n) * K + k0 + k] = f2bf(tile[k][n]);
    }
  } else if (b < 400) {
    // ---- precM: Mt[(h*256+e)][c] = sum_d Wq[c][h*32+d] * Wk[e][h*32+d] ----
    const int hb = b - 384;
    const int h = hb >> 1, eh = hb & 1;
    float (*wqS)[33] = (float (*)[33])smem;                    // 256x33
    float (*wkS)[33] = (float (*)[33])(smem + 256 * 33 * 4);   // 128x33
#pragma unroll
    for (int it = 0; it < 32; it++) {
      int lin = it * 256 + tid, r = lin >> 5, d = lin & 31;
      wqS[r][d] = Wq[(size_t)r * CC + h * DD + d];
    }
#pragma unroll
    for (int it = 0; it < 16; it++) {
      int lin = it * 256 + tid, r = lin >> 5, d = lin & 31;
      wkS[r][d] = Wk[(size_t)(eh * 128 + r) * CC + h * DD + d];
    }
    __syncthreads();
    const int w = tid >> 6, l = tid & 63;
    for (int ei = 0; ei < 32; ei++) {
      int e = w * 32 + ei;
      float o[4] = {0.f, 0.f, 0.f, 0.f};
#pragma unroll
      for (int d = 0; d < 32; d++) {
        float kv = wkS[e][d];
        o[0] += kv * wqS[l][d];
        o[1] += kv * wqS[l + 64][d];
        o[2] += kv * wqS[l + 128][d];
        o[3] += kv * wqS[l + 192][d];
      }
      size_t rowb = (size_t)(h * 256 + eh * 128 + e) * CC;
      Mt[rowb + l] = f2bf(o[0]);
      Mt[rowb + l + 64] = f2bf(o[1]);
      Mt[rowb + l + 128] = f2bf(o[2]);
      Mt[rowb + l + 192] = f2bf(o[3]);
    }
  } else {
    // ---- precWVM: WVMt[c][h*256+e] = sum_d Wv[e][h*32+d] * Wm[h*32+d][c] ----
    const int h = b - 400;
    float (*WvS)[33] = (float (*)[33])smem;                    // 256x33
    float (*WmS)[257] = (float (*)[257])(smem + 256 * 33 * 4); // 32x257
#pragma unroll
    for (int it = 0; it < 32; it++) {
      int lin = it * 256 + tid, e = lin >> 5, d = lin & 31;
      WvS[e][d] = Wv[(size_t)e * CC + h * DD + d];
    }
#pragma unroll
    for (int it = 0; it < 32; it++) {
      int lin = it * 256 + tid, d = lin >> 8, c = lin & 255;
      WmS[d][c] = Wm[(size_t)(h * DD + d) * CC + c];
    }
    __syncthreads();
    float wm[32];
#pragma unroll
    for (int d = 0; d < 32; d++) wm[d] = WmS[d][tid];
    for (int e = 0; e < 256; e++) {
      float acc = 0.f;
#pragma unroll
      for (int d = 0; d < 32; d++) acc += WvS[e][d] * wm[d];
      WVMt[(size_t)tid * 2048 + h * 256 + e] = f2bf(acc);
    }
  }
}

// ---------------------------------------------------------------------------
// QK GEMM: Out = A[M,256] @ Bt^T, BM=64 BN=256 BK=64, 512 thr, single-buffer.
// (validated round 11)
// ---------------------------------------------------------------------------
__global__ __launch_bounds__(512) void qk_gemm_kernel(
    const unsigned short* __restrict__ A, const unsigned short* __restrict__ Bt,
    unsigned short* __restrict__ Out, int K, int strideO) {
  __shared__ __align__(16) unsigned short As[64 * 64];    // 8 KB
  __shared__ __align__(16) unsigned short Bs[256 * 64];   // 32 KB
  const int tid = threadIdx.x;
  const int wv = tid >> 6, l = tid & 63;
  const int wr = wv >> 2, wc = wv & 3;
  const int lr = l & 15, lq = l >> 4;
  const int m0 = blockIdx.x * 64;
  const int n0 = blockIdx.y * 256;
  const int nsteps = K >> 6;

  f32x4_t acc[2][4];
#pragma unroll
  for (int m = 0; m < 2; m++)
#pragma unroll
    for (int n = 0; n < 4; n++) acc[m][n] = (f32x4_t){0.f, 0.f, 0.f, 0.f};

  const int rS = tid >> 3, sS = tid & 7, qS = sS ^ (rS & 7);

  for (int st = 0; st < nsteps; st++) {
    int kn = st * 64;
    gl_lds16(&A[(size_t)(m0 + rS) * K + kn + qS * 8], &As[tid * 8]);
#pragma unroll
    for (int it = 0; it < 4; it++) {
      int lin = it * 512 + tid, r = lin >> 3, s = lin & 7, q = s ^ (r & 7);
      gl_lds16(&Bt[(size_t)(n0 + r) * K + kn + q * 8], &Bs[lin * 8]);
    }
    __syncthreads();
#pragma unroll
    for (int kk = 0; kk < 2; kk++) {
      bf16x8_t af[2], bfr[4];
#pragma unroll
      for (int m = 0; m < 2; m++) {
        int r = wr * 32 + m * 16 + lr;
        int slot = (kk * 4 + lq) ^ (r & 7);
        af[m] = *(const bf16x8_t*)&As[r * 64 + slot * 8];
      }
#pragma unroll
      for (int n = 0; n < 4; n++) {
        int r = wc * 64 + n * 16 + lr;
        int slot = (kk * 4 + lq) ^ (r & 7);
        bfr[n] = *(const bf16x8_t*)&Bs[r * 64 + slot * 8];
      }
#pragma unroll
      for (int m = 0; m < 2; m++)
#pragma unroll
        for (int n = 0; n < 4; n++)
          acc[m][n] = __builtin_amdgcn_mfma_f32_16x16x32_bf16(af[m], bfr[n], acc[m][n], 0, 0, 0);
    }
    __syncthreads();
  }

#pragma unroll
  for (int m = 0; m < 2; m++)
#pragma unroll
    for (int n = 0; n < 4; n++)
#pragma unroll
      for (int j = 0; j < 4; j++) {
        int rl = wr * 32 + m * 16 + lq * 4 + j;
        int col = n0 + wc * 64 + n * 16 + lr;
        Out[(size_t)(m0 + rl) * strideO + col] = f2bf(acc[m][n][j]);
      }
}

// ---------------------------------------------------------------------------
// gemm1: hid = gelu([A||A2][M,512] @ Bt^T). BM=BN=128, BK=64 (validated r11).
// ---------------------------------------------------------------------------
__global__ __launch_bounds__(256) void gemm128_kernel(
    const unsigned short* __restrict__ A, const unsigned short* __restrict__ A2,
    const unsigned short* __restrict__ Bt, unsigned short* __restrict__ Out,
    int K, int strideO) {
  __shared__ __align__(16) unsigned short As[128 * 64];   // 16 KB
  __shared__ __align__(16) unsigned short Bs[128 * 64];   // 16 KB
  const int tid = threadIdx.x;
  const int wv = tid >> 6, l = tid & 63;
  const int wr = wv >> 1, wc = wv & 1;
  const int lr = l & 15, lq = l >> 4;
  const int m0 = blockIdx.x * 128;
  const int n0 = blockIdx.y * 128;
  const int nsteps = K >> 6;

  f32x4_t acc[4][4];
#pragma unroll
  for (int m = 0; m < 4; m++)
#pragma unroll
    for (int n = 0; n < 4; n++) acc[m][n] = (f32x4_t){0.f, 0.f, 0.f, 0.f};

  for (int st = 0; st < nsteps; st++) {
    int kn = st * 64;
#pragma unroll
    for (int it = 0; it < 4; it++) {
      int lin = it * 256 + tid, r = lin >> 3, s = lin & 7, q = s ^ (r & 7);
      int ka = kn + q * 8;
      const unsigned short* ap = (ka < 256) ? &A[(size_t)(m0 + r) * CC + ka]
                                            : &A2[(size_t)(m0 + r) * CC + ka - 256];
      gl_lds16(ap, &As[lin * 8]);
      gl_lds16(&Bt[(size_t)(n0 + r) * K + kn + q * 8], &Bs[lin * 8]);
    }
    __syncthreads();
#pragma unroll
    for (int kk = 0; kk < 2; kk++) {
      bf16x8_t af[4], bf[4];
#pragma unroll
      for (int m = 0; m < 4; m++) {
        int r = wr * 64 + m * 16 + lr;
        int slot = (kk * 4 + lq) ^ (r & 7);
        af[m] = *(const bf16x8_t*)&As[r * 64 + slot * 8];
      }
#pragma unroll
      for (int n = 0; n < 4; n++) {
        int r = wc * 64 + n * 16 + lr;
        int slot = (kk * 4 + lq) ^ (r & 7);
        bf[n] = *(const bf16x8_t*)&Bs[r * 64 + slot * 8];
      }
#pragma unroll
      for (int m = 0; m < 4; m++)
#pragma unroll
        for (int n = 0; n < 4; n++)
          acc[m][n] = __builtin_amdgcn_mfma_f32_16x16x32_bf16(af[m], bf[n], acc[m][n], 0, 0, 0);
    }
    __syncthreads();
  }

#pragma unroll
  for (int m = 0; m < 4; m++)
#pragma unroll
    for (int n = 0; n < 4; n++)
#pragma unroll
      for (int j = 0; j < 4; j++) {
        int row = m0 + wr * 64 + m * 16 + lq * 4 + j;
        int col = n0 + wc * 64 + n * 16 + lr;
        float x = acc[m][n][j];
        x = 0.5f * x * (1.0f + erff(x * 0.70710678118654752f));
        Out[(size_t)row * strideO + col] = f2bf(x);
      }
}

// ---------------------------------------------------------------------------
// attn2: per wave = one token (unchanged; validated rounds 6-11).
// ---------------------------------------------------------------------------
__global__ __launch_bounds__(256) void attn2_kernel(const unsigned short* __restrict__ QKc,
                                                    const float* __restrict__ target,
                                                    const float* __restrict__ wts,
                                                    const float* __restrict__ conf,
                                                    unsigned short* __restrict__ TC) {
  __shared__ __align__(16) unsigned short Ts[4][16 * 256];
  __shared__ float awL[4][PP][HH];
  const int tid = threadIdx.x;
  const int w = tid >> 6, l = tid & 63;
  const int t = blockIdx.x * 4 + w;
  const float* trow = target + (size_t)t * PP * CC;
  char* tsb = (char*)&Ts[w][0];

  {
    const int p = l >> 2;
#pragma unroll
    for (int i = 0; i < 8; i++) {
      int s = (l & 3) + i * 4;
      const float* gp = &trow[p * CC + s * 8];
      float4 v0 = *(const float4*)gp;
      float4 v1 = *(const float4*)(gp + 4);
      ushort4 u0 = make_ushort4(f2bf(v0.x), f2bf(v0.y), f2bf(v0.z), f2bf(v0.w));
      ushort4 u1 = make_ushort4(f2bf(v1.x), f2bf(v1.y), f2bf(v1.z), f2bf(v1.w));
      uint4 pk;
      pk.x = (unsigned)u0.x | ((unsigned)u0.y << 16);
      pk.y = (unsigned)u0.z | ((unsigned)u0.w << 16);
      pk.z = (unsigned)u1.x | ((unsigned)u1.y << 16);
      pk.w = (unsigned)u1.z | ((unsigned)u1.w << 16);
      *(uint4*)(tsb + p * 512 + ((s ^ (p & 7)) << 4)) = pk;
    }
  }

  f32x4_t sc4 = (f32x4_t){0.f, 0.f, 0.f, 0.f};
  {
    const int lr = l & 15, lq = l >> 4;
    const unsigned short* qkrow = QKc + (size_t)t * 2048 + (size_t)(lr & 7) * 256;
#pragma unroll
    for (int es = 0; es < 8; es++) {
      int slot = es * 4 + lq;
      bf16x8_t aF = *(const bf16x8_t*)(tsb + lr * 512 + ((slot ^ (lr & 7)) << 4));
      bf16x8_t bF = *(const bf16x8_t*)&qkrow[es * 32 + lq * 8];
      sc4 = __builtin_amdgcn_mfma_f32_16x16x32_bf16(aF, bF, sc4, 0, 0, 0);
    }
  }

  {
    const int g = l >> 4;
    const float rsD = 0.17677669529663687f;
    float sc[4], cf[4];
#pragma unroll
    for (int j = 0; j < 4; j++) {
      int p = g * 4 + j;
      sc[j] = sc4[j] * wts[(size_t)t * PP + p] * rsD;
      cf[j] = conf[(size_t)t * PP + p];
    }
    float mx = fmaxf(fmaxf(sc[0], sc[1]), fmaxf(sc[2], sc[3]));
    mx = fmaxf(mx, __shfl_xor(mx, 16, 64));
    mx = fmaxf(mx, __shfl_xor(mx, 32, 64));
    float ex[4], sm = 0.f;
#pragma unroll
    for (int j = 0; j < 4; j++) { ex[j] = expf(sc[j] - mx); sm += ex[j]; }
    sm += __shfl_xor(sm, 16, 64);
    sm += __shfl_xor(sm, 32, 64);
    float inv = 1.f / sm;
    if ((l & 15) < 8) {
#pragma unroll
      for (int j = 0; j < 4; j++) awL[w][g * 4 + j][l & 15] = ex[j] * inv * cf[j];
    }
  }

  float tc[HH][4];
#pragma unroll
  for (int h = 0; h < HH; h++)
#pragma unroll
    for (int j = 0; j < 4; j++) tc[h][j] = 0.f;
#pragma unroll
  for (int p = 0; p < PP; p++) {
    uint2 tv = *(const uint2*)(tsb + p * 512 + (((l >> 1) ^ (p & 7)) << 4) + (l & 1) * 8);
    float te0 = bf2f((unsigned short)(tv.x & 0xffff));
    float te1 = bf2f((unsigned short)(tv.x >> 16));
    float te2 = bf2f((unsigned short)(tv.y & 0xffff));
    float te3 = bf2f((unsigned short)(tv.y >> 16));
#pragma unroll
    for (int h = 0; h < HH; h++) {
      float a = awL[w][p][h];
      tc[h][0] += a * te0; tc[h][1] += a * te1;
      tc[h][2] += a * te2; tc[h][3] += a * te3;
    }
  }
  size_t tcb = (size_t)t * 2048;
#pragma unroll
  for (int h = 0; h < HH; h++) {
    ushort4 o = make_ushort4(f2bf(tc[h][0]), f2bf(tc[h][1]), f2bf(tc[h][2]), f2bf(tc[h][3]));
    *(ushort4*)&TC[tcb + h * 256 + 4 * l] = o;
  }
}

// ---------------------------------------------------------------------------
// nwide GEMM (BM=32, BN=256, K=2048), BK=128 single-buffer: 32 MFMA per
// barrier pair, 16 K-steps. Grid-limited to 2 blocks/CU so the 73KB LDS
// is occupancy-free. 16-slot XOR swizzle s^(r&15).
// EPI: 0 = LN -> bf16; 1 = LN + residual -> f32.
// ---------------------------------------------------------------------------
template<int EPI>
__global__ __launch_bounds__(256) void nwide_gemm_kernel(
    const unsigned short* __restrict__ A, const unsigned short* __restrict__ Bt,
    unsigned short* __restrict__ OutB, float* __restrict__ OutF,
    const float* __restrict__ gam, const float* __restrict__ bet,
    const float* __restrict__ res) {
  __shared__ __align__(16) unsigned short As[32 * 128];    // 8 KB
  __shared__ __align__(16) unsigned short Bs[256 * 128];   // 64 KB
  __shared__ float redS[32][5], redQ[32][5];
  const int tid = threadIdx.x;
  const int wc = tid >> 6, l = tid & 63;
  const int lr = l & 15, lq = l >> 4;
  const int m0 = blockIdx.x * 32;
  const int K = 2048;

  f32x4_t acc[2][4];
#pragma unroll
  for (int m = 0; m < 2; m++)
#pragma unroll
    for (int n = 0; n < 4; n++) acc[m][n] = (f32x4_t){0.f, 0.f, 0.f, 0.f};

  for (int st = 0; st < 16; st++) {
    int kn = st * 128;
    // A: 32 rows x 128 k = 512 x 16B chunks, 2 per thread
#pragma unroll
    for (int it = 0; it < 2; it++) {
      int lin = it * 256 + tid, r = lin >> 4, s = lin & 15, q = s ^ (r & 15);
      gl_lds16(&A[(size_t)(m0 + r) * K + kn + q * 8], &As[lin * 8]);
    }
    // B: 256 rows x 128 k = 4096 chunks, 16 per thread
#pragma unroll
    for (int it = 0; it < 16; it++) {
      int lin = it * 256 + tid, r = lin >> 4, s = lin & 15, q = s ^ (r & 15);
      gl_lds16(&Bt[(size_t)r * K + kn + q * 8], &Bs[lin * 8]);
    }
    __syncthreads();
#pragma unroll
    for (int kk = 0; kk < 4; kk++) {
      bf16x8_t af[2], bfr[4];
#pragma unroll
      for (int m = 0; m < 2; m++) {
        int r = m * 16 + lr;
        int slot = (kk * 4 + lq) ^ (r & 15);
        af[m] = *(const bf16x8_t*)&As[r * 128 + slot * 8];
      }
#pragma unroll
      for (int n = 0; n < 4; n++) {
        int r = wc * 64 + n * 16 + lr;
        int slot = (kk * 4 + lq) ^ (r & 15);
        bfr[n] = *(const bf16x8_t*)&Bs[r * 128 + slot * 8];
      }
#pragma unroll
      for (int m = 0; m < 2; m++)
#pragma unroll
        for (int n = 0; n < 4; n++)
          acc[m][n] = __builtin_amdgcn_mfma_f32_16x16x32_bf16(af[m], bfr[n], acc[m][n], 0, 0, 0);
    }
    __syncthreads();
  }

  // LN epilogue (block covers the full 256-col row)
  float s1[2][4], s2[2][4];
#pragma unroll
  for (int m = 0; m < 2; m++)
#pragma unroll
    for (int j = 0; j < 4; j++) {
      float a = 0.f, b = 0.f;
#pragma unroll
      for (int n = 0; n < 4; n++) { float x = acc[m][n][j]; a += x; b += x * x; }
      s1[m][j] = a; s2[m][j] = b;
    }
#pragma unroll
  for (int mask = 1; mask < 16; mask <<= 1)
#pragma unroll
    for (int m = 0; m < 2; m++)
#pragma unroll
      for (int j = 0; j < 4; j++) {
        s1[m][j] += __shfl_xor(s1[m][j], mask, 64);
        s2[m][j] += __shfl_xor(s2[m][j], mask, 64);
      }
  if (lr == 0) {
#pragma unroll
    for (int m = 0; m < 2; m++)
#pragma unroll
      for (int j = 0; j < 4; j++) {
        int rl = m * 16 + lq * 4 + j;
        redS[rl][wc] = s1[m][j];
        redQ[rl][wc] = s2[m][j];
      }
  }
  __syncthreads();
#pragma unroll
  for (int m = 0; m < 2; m++)
#pragma unroll
    for (int j = 0; j < 4; j++) {
      int rl = m * 16 + lq * 4 + j;
      float ts = redS[rl][0] + redS[rl][1] + redS[rl][2] + redS[rl][3];
      float tq = redQ[rl][0] + redQ[rl][1] + redQ[rl][2] + redQ[rl][3];
      float mu = ts * (1.f / 256.f);
      float var = tq * (1.f / 256.f) - mu * mu;
      float rs = rsqrtf(var + LN_EPS);
      size_t rowg = (size_t)(m0 + rl);
#pragma unroll
      for (int n = 0; n < 4; n++) {
        int col = wc * 64 + n * 16 + lr;
        float v = (acc[m][n][j] - mu) * rs * gam[col] + bet[col];
        if constexpr (EPI == 0) {
          OutB[rowg * CC + col] = f2bf(v);
        } else {
          OutF[rowg * CC + col] = res[rowg * CC + col] + v;
        }
      }
    }
}

extern "C" void kernel_launch(void* const* d_in, const int* in_sizes, int n_in,
                              void* d_out, int out_size, void* d_ws, size_t ws_size,
                              hipStream_t stream) {
  const float* source = (const float*)d_in[0];
  const float* target = (const float*)d_in[1];
  const float* weights = (const float*)d_in[2];
  const float* conf   = (const float*)d_in[3];
  const float* Wq = (const float*)d_in[4];
  const float* Wk = (const float*)d_in[5];
  const float* Wv = (const float*)d_in[6];
  const float* Wm = (const float*)d_in[7];
  const float* g1 = (const float*)d_in[8];
  const float* b1 = (const float*)d_in[9];
  const float* Wf1 = (const float*)d_in[10];
  const float* Wf2 = (const float*)d_in[11];
  const float* g2 = (const float*)d_in[12];
  const float* b2 = (const float*)d_in[13];
  float* out = (float*)d_out;

  unsigned short* SB   = (unsigned short*)d_ws;                 // [16384][256]
  unsigned short* MSGb = SB + (size_t)T_TOK * CC;               // [16384][256]
  unsigned short* Mt   = MSGb + (size_t)T_TOK * CC;             // [2048][256]
  unsigned short* WVMt = Mt + (size_t)2048 * 256;               // [256][2048]
  unsigned short* WF1t = WVMt + (size_t)256 * 2048;             // [2048][512]
  unsigned short* WF2t = WF1t + (size_t)2048 * 512;             // [256][2048]
  unsigned short* BIG1 = WF2t + (size_t)256 * 2048;             // QKc, later hid
  unsigned short* BIG2 = BIG1 + (size_t)T_TOK * 2048;           // TC
  unsigned short* QKc  = BIG1;
  unsigned short* hid  = BIG1;
  unsigned short* TC   = BIG2;

  // prep
  cvt_bf16_kernel<<<T_TOK * CC / 1024, 256, 0, stream>>>(source, SB);
  prep_small_kernel<<<408, 256, 0, stream>>>(Wf1, Wf2, Wq, Wk, Wv, Wm,
                                             WF1t, WF2t, Mt, WVMt);

  // attention pipeline: QKc = SB @ Mt^T
  qk_gemm_kernel<<<dim3(T_TOK / 64, 8), 512, 0, stream>>>(SB, Mt, QKc, 256, 2048);
  attn2_kernel<<<T_TOK / 4, 256, 0, stream>>>(QKc, target, weights, conf, TC);
  // message = LN(TC @ WVMt^T)
  nwide_gemm_kernel<0><<<T_TOK / 32, 256, 0, stream>>>(
      TC, WVMt, MSGb, nullptr, g1, b1, nullptr);

  // FFN: hid = gelu([SB||MSG] @ W1t^T)
  gemm128_kernel<<<dim3(T_TOK / 128, 16), 256, 0, stream>>>(
      SB, MSGb, WF1t, hid, 512, 2048);
  // out = src + LN(hid @ W2t^T)
  nwide_gemm_kernel<1><<<T_TOK / 32, 256, 0, stream>>>(
      hid, WF2t, nullptr, out, g2, b2, source);
}

// Round 13
// 294.205 us; speedup vs baseline: 1.2518x; 1.0289x over previous
//
#include <hip/hip_runtime.h>
#include <hip/hip_bf16.h>
#include <math.h>

#define T_TOK 16384
#define CC 256
#define PP 16
#define HH 8
#define DD 32
#define LN_EPS 1e-5f

typedef __attribute__((ext_vector_type(8))) short bf16x8_t;
typedef __attribute__((ext_vector_type(4))) float f32x4_t;

__device__ __forceinline__ unsigned short f2bf(float x) {
  __hip_bfloat16 h = __float2bfloat16(x);
  return *reinterpret_cast<unsigned short*>(&h);
}
__device__ __forceinline__ float bf2f(unsigned short u) {
  union { unsigned int i; float f; } v; v.i = ((unsigned int)u) << 16; return v.f;
}
// async global->LDS, 16B per lane; LDS dest must be wave-uniform base + lane*16
__device__ __forceinline__ void gl_lds16(const unsigned short* g, unsigned short* l) {
  __builtin_amdgcn_global_load_lds(
      (const __attribute__((address_space(1))) unsigned int*)g,
      (__attribute__((address_space(3))) unsigned int*)l, 16, 0, 0);
}

// ---------------------------------------------------------------------------
// cvt: f32 -> bf16 rowmajor copy (source -> SB)
// ---------------------------------------------------------------------------
__global__ __launch_bounds__(256) void cvt_bf16_kernel(const float* __restrict__ src,
                                                       unsigned short* __restrict__ dst) {
  int i = (blockIdx.x * 256 + threadIdx.x) * 4;
  float4 v = *(const float4*)&src[i];
  ushort4 o = make_ushort4(f2bf(v.x), f2bf(v.y), f2bf(v.z), f2bf(v.w));
  *(ushort4*)&dst[i] = o;
}

// ---------------------------------------------------------------------------
// Fused small preps (validated round 12): [0,256) T(Wf1); [256,384) T(Wf2);
// [384,400) precM; [400,408) precWVM.
// ---------------------------------------------------------------------------
__global__ __launch_bounds__(256) void prep_small_kernel(
    const float* __restrict__ Wf1, const float* __restrict__ Wf2,
    const float* __restrict__ Wq, const float* __restrict__ Wk,
    const float* __restrict__ Wv, const float* __restrict__ Wm,
    unsigned short* __restrict__ WF1t, unsigned short* __restrict__ WF2t,
    unsigned short* __restrict__ Mt, unsigned short* __restrict__ WVMt) {
  __shared__ __align__(16) char smem[66688];
  const int b = blockIdx.x;
  const int tid = threadIdx.x;

  if (b < 384) {
    const float* src; unsigned short* dst; int K, N, k0, n0;
    if (b < 256) { src = Wf1; dst = WF1t; K = 512;  N = 2048; k0 = (b & 7) * 64;  n0 = (b >> 3) * 64; }
    else { int bb = b - 256; src = Wf2; dst = WF2t; K = 2048; N = 256;  k0 = (bb & 31) * 64; n0 = (bb >> 5) * 64; }
    float (*tile)[65] = (float (*)[65])smem;
#pragma unroll
    for (int i = 0; i < 16; i++) {
      int lin = i * 256 + tid, r = lin >> 6, c = lin & 63;
      tile[r][c] = src[(size_t)(k0 + r) * N + n0 + c];
    }
    __syncthreads();
#pragma unroll
    for (int i = 0; i < 16; i++) {
      int lin = i * 256 + tid, n = lin >> 6, k = lin & 63;
      dst[(size_t)(n0 + n) * K + k0 + k] = f2bf(tile[k][n]);
    }
  } else if (b < 400) {
    const int hb = b - 384;
    const int h = hb >> 1, eh = hb & 1;
    float (*wqS)[33] = (float (*)[33])smem;
    float (*wkS)[33] = (float (*)[33])(smem + 256 * 33 * 4);
#pragma unroll
    for (int it = 0; it < 32; it++) {
      int lin = it * 256 + tid, r = lin >> 5, d = lin & 31;
      wqS[r][d] = Wq[(size_t)r * CC + h * DD + d];
    }
#pragma unroll
    for (int it = 0; it < 16; it++) {
      int lin = it * 256 + tid, r = lin >> 5, d = lin & 31;
      wkS[r][d] = Wk[(size_t)(eh * 128 + r) * CC + h * DD + d];
    }
    __syncthreads();
    const int w = tid >> 6, l = tid & 63;
    for (int ei = 0; ei < 32; ei++) {
      int e = w * 32 + ei;
      float o[4] = {0.f, 0.f, 0.f, 0.f};
#pragma unroll
      for (int d = 0; d < 32; d++) {
        float kv = wkS[e][d];
        o[0] += kv * wqS[l][d];
        o[1] += kv * wqS[l + 64][d];
        o[2] += kv * wqS[l + 128][d];
        o[3] += kv * wqS[l + 192][d];
      }
      size_t rowb = (size_t)(h * 256 + eh * 128 + e) * CC;
      Mt[rowb + l] = f2bf(o[0]);
      Mt[rowb + l + 64] = f2bf(o[1]);
      Mt[rowb + l + 128] = f2bf(o[2]);
      Mt[rowb + l + 192] = f2bf(o[3]);
    }
  } else {
    const int h = b - 400;
    float (*WvS)[33] = (float (*)[33])smem;
    float (*WmS)[257] = (float (*)[257])(smem + 256 * 33 * 4);
#pragma unroll
    for (int it = 0; it < 32; it++) {
      int lin = it * 256 + tid, e = lin >> 5, d = lin & 31;
      WvS[e][d] = Wv[(size_t)e * CC + h * DD + d];
    }
#pragma unroll
    for (int it = 0; it < 32; it++) {
      int lin = it * 256 + tid, d = lin >> 8, c = lin & 255;
      WmS[d][c] = Wm[(size_t)(h * DD + d) * CC + c];
    }
    __syncthreads();
    float wm[32];
#pragma unroll
    for (int d = 0; d < 32; d++) wm[d] = WmS[d][tid];
    for (int e = 0; e < 256; e++) {
      float acc = 0.f;
#pragma unroll
      for (int d = 0; d < 32; d++) acc += WvS[e][d] * wm[d];
      WVMt[(size_t)tid * 2048 + h * 256 + e] = f2bf(acc);
    }
  }
}

// ---------------------------------------------------------------------------
// QK GEMM: Out = A[M,256] @ Bt^T, BM=64 BN=256 BK=64, 512 thr (validated r11).
// ---------------------------------------------------------------------------
__global__ __launch_bounds__(512) void qk_gemm_kernel(
    const unsigned short* __restrict__ A, const unsigned short* __restrict__ Bt,
    unsigned short* __restrict__ Out, int K, int strideO) {
  __shared__ __align__(16) unsigned short As[64 * 64];    // 8 KB
  __shared__ __align__(16) unsigned short Bs[256 * 64];   // 32 KB
  const int tid = threadIdx.x;
  const int wv = tid >> 6, l = tid & 63;
  const int wr = wv >> 2, wc = wv & 3;
  const int lr = l & 15, lq = l >> 4;
  const int m0 = blockIdx.x * 64;
  const int n0 = blockIdx.y * 256;
  const int nsteps = K >> 6;

  f32x4_t acc[2][4];
#pragma unroll
  for (int m = 0; m < 2; m++)
#pragma unroll
    for (int n = 0; n < 4; n++) acc[m][n] = (f32x4_t){0.f, 0.f, 0.f, 0.f};

  const int rS = tid >> 3, sS = tid & 7, qS = sS ^ (rS & 7);

  for (int st = 0; st < nsteps; st++) {
    int kn = st * 64;
    gl_lds16(&A[(size_t)(m0 + rS) * K + kn + qS * 8], &As[tid * 8]);
#pragma unroll
    for (int it = 0; it < 4; it++) {
      int lin = it * 512 + tid, r = lin >> 3, s = lin & 7, q = s ^ (r & 7);
      gl_lds16(&Bt[(size_t)(n0 + r) * K + kn + q * 8], &Bs[lin * 8]);
    }
    __syncthreads();
#pragma unroll
    for (int kk = 0; kk < 2; kk++) {
      bf16x8_t af[2], bfr[4];
#pragma unroll
      for (int m = 0; m < 2; m++) {
        int r = wr * 32 + m * 16 + lr;
        int slot = (kk * 4 + lq) ^ (r & 7);
        af[m] = *(const bf16x8_t*)&As[r * 64 + slot * 8];
      }
#pragma unroll
      for (int n = 0; n < 4; n++) {
        int r = wc * 64 + n * 16 + lr;
        int slot = (kk * 4 + lq) ^ (r & 7);
        bfr[n] = *(const bf16x8_t*)&Bs[r * 64 + slot * 8];
      }
#pragma unroll
      for (int m = 0; m < 2; m++)
#pragma unroll
        for (int n = 0; n < 4; n++)
          acc[m][n] = __builtin_amdgcn_mfma_f32_16x16x32_bf16(af[m], bfr[n], acc[m][n], 0, 0, 0);
    }
    __syncthreads();
  }

#pragma unroll
  for (int m = 0; m < 2; m++)
#pragma unroll
    for (int n = 0; n < 4; n++)
#pragma unroll
      for (int j = 0; j < 4; j++) {
        int rl = wr * 32 + m * 16 + lq * 4 + j;
        int col = n0 + wc * 64 + n * 16 + lr;
        Out[(size_t)(m0 + rl) * strideO + col] = f2bf(acc[m][n][j]);
      }
}

// ---------------------------------------------------------------------------
// gemm1: hid = gelu([A||A2][M,512] @ Bt^T). BM=128, BN=256, BK=64, 512 thr,
// 8 waves (2 wr x 4 wc), wave tile 64x64; single-buffer; 32 MFMA/barrier-pair.
// ---------------------------------------------------------------------------
__global__ __launch_bounds__(512) void gemm1_kernel(
    const unsigned short* __restrict__ A, const unsigned short* __restrict__ A2,
    const unsigned short* __restrict__ Bt, unsigned short* __restrict__ Out,
    int K, int strideO) {
  __shared__ __align__(16) unsigned short As[128 * 64];   // 16 KB
  __shared__ __align__(16) unsigned short Bs[256 * 64];   // 32 KB
  const int tid = threadIdx.x;
  const int wv = tid >> 6, l = tid & 63;
  const int wr = wv >> 2, wc = wv & 3;
  const int lr = l & 15, lq = l >> 4;
  const int m0 = blockIdx.x * 128;
  const int n0 = blockIdx.y * 256;
  const int nsteps = K >> 6;

  f32x4_t acc[4][4];
#pragma unroll
  for (int m = 0; m < 4; m++)
#pragma unroll
    for (int n = 0; n < 4; n++) acc[m][n] = (f32x4_t){0.f, 0.f, 0.f, 0.f};

  for (int st = 0; st < nsteps; st++) {
    int kn = st * 64;
    // A: 128 rows x 64 k = 1024 x 16B chunks, 2 per thread (concat over k)
#pragma unroll
    for (int it = 0; it < 2; it++) {
      int lin = it * 512 + tid, r = lin >> 3, s = lin & 7, q = s ^ (r & 7);
      int ka = kn + q * 8;
      const unsigned short* ap = (ka < 256) ? &A[(size_t)(m0 + r) * CC + ka]
                                            : &A2[(size_t)(m0 + r) * CC + ka - 256];
      gl_lds16(ap, &As[lin * 8]);
    }
    // B: 256 rows x 64 k = 2048 chunks, 4 per thread
#pragma unroll
    for (int it = 0; it < 4; it++) {
      int lin = it * 512 + tid, r = lin >> 3, s = lin & 7, q = s ^ (r & 7);
      gl_lds16(&Bt[(size_t)(n0 + r) * K + kn + q * 8], &Bs[lin * 8]);
    }
    __syncthreads();
#pragma unroll
    for (int kk = 0; kk < 2; kk++) {
      bf16x8_t af[4], bf[4];
#pragma unroll
      for (int m = 0; m < 4; m++) {
        int r = wr * 64 + m * 16 + lr;
        int slot = (kk * 4 + lq) ^ (r & 7);
        af[m] = *(const bf16x8_t*)&As[r * 64 + slot * 8];
      }
#pragma unroll
      for (int n = 0; n < 4; n++) {
        int r = wc * 64 + n * 16 + lr;
        int slot = (kk * 4 + lq) ^ (r & 7);
        bf[n] = *(const bf16x8_t*)&Bs[r * 64 + slot * 8];
      }
#pragma unroll
      for (int m = 0; m < 4; m++)
#pragma unroll
        for (int n = 0; n < 4; n++)
          acc[m][n] = __builtin_amdgcn_mfma_f32_16x16x32_bf16(af[m], bf[n], acc[m][n], 0, 0, 0);
    }
    __syncthreads();
  }

#pragma unroll
  for (int m = 0; m < 4; m++)
#pragma unroll
    for (int n = 0; n < 4; n++)
#pragma unroll
      for (int j = 0; j < 4; j++) {
        int row = m0 + wr * 64 + m * 16 + lq * 4 + j;
        int col = n0 + wc * 64 + n * 16 + lr;
        float x = acc[m][n][j];
        x = 0.5f * x * (1.0f + erff(x * 0.70710678118654752f));
        Out[(size_t)row * strideO + col] = f2bf(x);
      }
}

// ---------------------------------------------------------------------------
// attn2: per wave = one token (unchanged; validated rounds 6-12).
// ---------------------------------------------------------------------------
__global__ __launch_bounds__(256) void attn2_kernel(const unsigned short* __restrict__ QKc,
                                                    const float* __restrict__ target,
                                                    const float* __restrict__ wts,
                                                    const float* __restrict__ conf,
                                                    unsigned short* __restrict__ TC) {
  __shared__ __align__(16) unsigned short Ts[4][16 * 256];
  __shared__ float awL[4][PP][HH];
  const int tid = threadIdx.x;
  const int w = tid >> 6, l = tid & 63;
  const int t = blockIdx.x * 4 + w;
  const float* trow = target + (size_t)t * PP * CC;
  char* tsb = (char*)&Ts[w][0];

  {
    const int p = l >> 2;
#pragma unroll
    for (int i = 0; i < 8; i++) {
      int s = (l & 3) + i * 4;
      const float* gp = &trow[p * CC + s * 8];
      float4 v0 = *(const float4*)gp;
      float4 v1 = *(const float4*)(gp + 4);
      ushort4 u0 = make_ushort4(f2bf(v0.x), f2bf(v0.y), f2bf(v0.z), f2bf(v0.w));
      ushort4 u1 = make_ushort4(f2bf(v1.x), f2bf(v1.y), f2bf(v1.z), f2bf(v1.w));
      uint4 pk;
      pk.x = (unsigned)u0.x | ((unsigned)u0.y << 16);
      pk.y = (unsigned)u0.z | ((unsigned)u0.w << 16);
      pk.z = (unsigned)u1.x | ((unsigned)u1.y << 16);
      pk.w = (unsigned)u1.z | ((unsigned)u1.w << 16);
      *(uint4*)(tsb + p * 512 + ((s ^ (p & 7)) << 4)) = pk;
    }
  }

  f32x4_t sc4 = (f32x4_t){0.f, 0.f, 0.f, 0.f};
  {
    const int lr = l & 15, lq = l >> 4;
    const unsigned short* qkrow = QKc + (size_t)t * 2048 + (size_t)(lr & 7) * 256;
#pragma unroll
    for (int es = 0; es < 8; es++) {
      int slot = es * 4 + lq;
      bf16x8_t aF = *(const bf16x8_t*)(tsb + lr * 512 + ((slot ^ (lr & 7)) << 4));
      bf16x8_t bF = *(const bf16x8_t*)&qkrow[es * 32 + lq * 8];
      sc4 = __builtin_amdgcn_mfma_f32_16x16x32_bf16(aF, bF, sc4, 0, 0, 0);
    }
  }

  {
    const int g = l >> 4;
    const float rsD = 0.17677669529663687f;
    float sc[4], cf[4];
#pragma unroll
    for (int j = 0; j < 4; j++) {
      int p = g * 4 + j;
      sc[j] = sc4[j] * wts[(size_t)t * PP + p] * rsD;
      cf[j] = conf[(size_t)t * PP + p];
    }
    float mx = fmaxf(fmaxf(sc[0], sc[1]), fmaxf(sc[2], sc[3]));
    mx = fmaxf(mx, __shfl_xor(mx, 16, 64));
    mx = fmaxf(mx, __shfl_xor(mx, 32, 64));
    float ex[4], sm = 0.f;
#pragma unroll
    for (int j = 0; j < 4; j++) { ex[j] = expf(sc[j] - mx); sm += ex[j]; }
    sm += __shfl_xor(sm, 16, 64);
    sm += __shfl_xor(sm, 32, 64);
    float inv = 1.f / sm;
    if ((l & 15) < 8) {
#pragma unroll
      for (int j = 0; j < 4; j++) awL[w][g * 4 + j][l & 15] = ex[j] * inv * cf[j];
    }
  }

  float tc[HH][4];
#pragma unroll
  for (int h = 0; h < HH; h++)
#pragma unroll
    for (int j = 0; j < 4; j++) tc[h][j] = 0.f;
#pragma unroll
  for (int p = 0; p < PP; p++) {
    uint2 tv = *(const uint2*)(tsb + p * 512 + (((l >> 1) ^ (p & 7)) << 4) + (l & 1) * 8);
    float te0 = bf2f((unsigned short)(tv.x & 0xffff));
    float te1 = bf2f((unsigned short)(tv.x >> 16));
    float te2 = bf2f((unsigned short)(tv.y & 0xffff));
    float te3 = bf2f((unsigned short)(tv.y >> 16));
#pragma unroll
    for (int h = 0; h < HH; h++) {
      float a = awL[w][p][h];
      tc[h][0] += a * te0; tc[h][1] += a * te1;
      tc[h][2] += a * te2; tc[h][3] += a * te3;
    }
  }
  size_t tcb = (size_t)t * 2048;
#pragma unroll
  for (int h = 0; h < HH; h++) {
    ushort4 o = make_ushort4(f2bf(tc[h][0]), f2bf(tc[h][1]), f2bf(tc[h][2]), f2bf(tc[h][3]));
    *(ushort4*)&TC[tcb + h * 256 + 4 * l] = o;
  }
}

// ---------------------------------------------------------------------------
// nwide GEMM (BM=32, BN=256, K=2048), BK=128 single-buffer (validated r12).
// EPI: 0 = LN -> bf16; 1 = LN + residual -> f32.
// ---------------------------------------------------------------------------
template<int EPI>
__global__ __launch_bounds__(256) void nwide_gemm_kernel(
    const unsigned short* __restrict__ A, const unsigned short* __restrict__ Bt,
    unsigned short* __restrict__ OutB, float* __restrict__ OutF,
    const float* __restrict__ gam, const float* __restrict__ bet,
    const float* __restrict__ res) {
  __shared__ __align__(16) unsigned short As[32 * 128];    // 8 KB
  __shared__ __align__(16) unsigned short Bs[256 * 128];   // 64 KB
  __shared__ float redS[32][5], redQ[32][5];
  const int tid = threadIdx.x;
  const int wc = tid >> 6, l = tid & 63;
  const int lr = l & 15, lq = l >> 4;
  const int m0 = blockIdx.x * 32;
  const int K = 2048;

  f32x4_t acc[2][4];
#pragma unroll
  for (int m = 0; m < 2; m++)
#pragma unroll
    for (int n = 0; n < 4; n++) acc[m][n] = (f32x4_t){0.f, 0.f, 0.f, 0.f};

  for (int st = 0; st < 16; st++) {
    int kn = st * 128;
#pragma unroll
    for (int it = 0; it < 2; it++) {
      int lin = it * 256 + tid, r = lin >> 4, s = lin & 15, q = s ^ (r & 15);
      gl_lds16(&A[(size_t)(m0 + r) * K + kn + q * 8], &As[lin * 8]);
    }
#pragma unroll
    for (int it = 0; it < 16; it++) {
      int lin = it * 256 + tid, r = lin >> 4, s = lin & 15, q = s ^ (r & 15);
      gl_lds16(&Bt[(size_t)r * K + kn + q * 8], &Bs[lin * 8]);
    }
    __syncthreads();
#pragma unroll
    for (int kk = 0; kk < 4; kk++) {
      bf16x8_t af[2], bfr[4];
#pragma unroll
      for (int m = 0; m < 2; m++) {
        int r = m * 16 + lr;
        int slot = (kk * 4 + lq) ^ (r & 15);
        af[m] = *(const bf16x8_t*)&As[r * 128 + slot * 8];
      }
#pragma unroll
      for (int n = 0; n < 4; n++) {
        int r = wc * 64 + n * 16 + lr;
        int slot = (kk * 4 + lq) ^ (r & 15);
        bfr[n] = *(const bf16x8_t*)&Bs[r * 128 + slot * 8];
      }
#pragma unroll
      for (int m = 0; m < 2; m++)
#pragma unroll
        for (int n = 0; n < 4; n++)
          acc[m][n] = __builtin_amdgcn_mfma_f32_16x16x32_bf16(af[m], bfr[n], acc[m][n], 0, 0, 0);
    }
    __syncthreads();
  }

  // LN epilogue (block covers the full 256-col row)
  float s1[2][4], s2[2][4];
#pragma unroll
  for (int m = 0; m < 2; m++)
#pragma unroll
    for (int j = 0; j < 4; j++) {
      float a = 0.f, b = 0.f;
#pragma unroll
      for (int n = 0; n < 4; n++) { float x = acc[m][n][j]; a += x; b += x * x; }
      s1[m][j] = a; s2[m][j] = b;
    }
#pragma unroll
  for (int mask = 1; mask < 16; mask <<= 1)
#pragma unroll
    for (int m = 0; m < 2; m++)
#pragma unroll
      for (int j = 0; j < 4; j++) {
        s1[m][j] += __shfl_xor(s1[m][j], mask, 64);
        s2[m][j] += __shfl_xor(s2[m][j], mask, 64);
      }
  if (lr == 0) {
#pragma unroll
    for (int m = 0; m < 2; m++)
#pragma unroll
      for (int j = 0; j < 4; j++) {
        int rl = m * 16 + lq * 4 + j;
        redS[rl][wc] = s1[m][j];
        redQ[rl][wc] = s2[m][j];
      }
  }
  __syncthreads();
#pragma unroll
  for (int m = 0; m < 2; m++)
#pragma unroll
    for (int j = 0; j < 4; j++) {
      int rl = m * 16 + lq * 4 + j;
      float ts = redS[rl][0] + redS[rl][1] + redS[rl][2] + redS[rl][3];
      float tq = redQ[rl][0] + redQ[rl][1] + redQ[rl][2] + redQ[rl][3];
      float mu = ts * (1.f / 256.f);
      float var = tq * (1.f / 256.f) - mu * mu;
      float rs = rsqrtf(var + LN_EPS);
      size_t rowg = (size_t)(m0 + rl);
#pragma unroll
      for (int n = 0; n < 4; n++) {
        int col = wc * 64 + n * 16 + lr;
        float v = (acc[m][n][j] - mu) * rs * gam[col] + bet[col];
        if constexpr (EPI == 0) {
          OutB[rowg * CC + col] = f2bf(v);
        } else {
          OutF[rowg * CC + col] = res[rowg * CC + col] + v;
        }
      }
    }
}

extern "C" void kernel_launch(void* const* d_in, const int* in_sizes, int n_in,
                              void* d_out, int out_size, void* d_ws, size_t ws_size,
                              hipStream_t stream) {
  const float* source = (const float*)d_in[0];
  const float* target = (const float*)d_in[1];
  const float* weights = (const float*)d_in[2];
  const float* conf   = (const float*)d_in[3];
  const float* Wq = (const float*)d_in[4];
  const float* Wk = (const float*)d_in[5];
  const float* Wv = (const float*)d_in[6];
  const float* Wm = (const float*)d_in[7];
  const float* g1 = (const float*)d_in[8];
  const float* b1 = (const float*)d_in[9];
  const float* Wf1 = (const float*)d_in[10];
  const float* Wf2 = (const float*)d_in[11];
  const float* g2 = (const float*)d_in[12];
  const float* b2 = (const float*)d_in[13];
  float* out = (float*)d_out;

  unsigned short* SB   = (unsigned short*)d_ws;                 // [16384][256]
  unsigned short* MSGb = SB + (size_t)T_TOK * CC;               // [16384][256]
  unsigned short* Mt   = MSGb + (size_t)T_TOK * CC;             // [2048][256]
  unsigned short* WVMt = Mt + (size_t)2048 * 256;               // [256][2048]
  unsigned short* WF1t = WVMt + (size_t)256 * 2048;             // [2048][512]
  unsigned short* WF2t = WF1t + (size_t)2048 * 512;             // [256][2048]
  unsigned short* BIG1 = WF2t + (size_t)256 * 2048;             // QKc, later hid
  unsigned short* BIG2 = BIG1 + (size_t)T_TOK * 2048;           // TC
  unsigned short* QKc  = BIG1;
  unsigned short* hid  = BIG1;
  unsigned short* TC   = BIG2;

  // prep
  cvt_bf16_kernel<<<T_TOK * CC / 1024, 256, 0, stream>>>(source, SB);
  prep_small_kernel<<<408, 256, 0, stream>>>(Wf1, Wf2, Wq, Wk, Wv, Wm,
                                             WF1t, WF2t, Mt, WVMt);

  // attention pipeline: QKc = SB @ Mt^T
  qk_gemm_kernel<<<dim3(T_TOK / 64, 8), 512, 0, stream>>>(SB, Mt, QKc, 256, 2048);
  attn2_kernel<<<T_TOK / 4, 256, 0, stream>>>(QKc, target, weights, conf, TC);
  // message = LN(TC @ WVMt^T)
  nwide_gemm_kernel<0><<<T_TOK / 32, 256, 0, stream>>>(
      TC, WVMt, MSGb, nullptr, g1, b1, nullptr);

  // FFN: hid = gelu([SB||MSG] @ W1t^T)  (128x256 tiles)
  gemm1_kernel<<<dim3(T_TOK / 128, 8), 512, 0, stream>>>(
      SB, MSGb, WF1t, hid, 512, 2048);
  // out = src + LN(hid @ W2t^T)
  nwide_gemm_kernel<1><<<T_TOK / 32, 256, 0, stream>>>(
      hid, WF2t, nullptr, out, g2, b2, source);
}

// Round 14
// 294.183 us; speedup vs baseline: 1.2519x; 1.0001x over previous
//
#include <hip/hip_runtime.h>
#include <hip/hip_bf16.h>
#include <math.h>

#define T_TOK 16384
#define CC 256
#define PP 16
#define HH 8
#define DD 32
#define LN_EPS 1e-5f

typedef __attribute__((ext_vector_type(8))) short bf16x8_t;
typedef __attribute__((ext_vector_type(4))) float f32x4_t;

__device__ __forceinline__ unsigned short f2bf(float x) {
  __hip_bfloat16 h = __float2bfloat16(x);
  return *reinterpret_cast<unsigned short*>(&h);
}
__device__ __forceinline__ float bf2f(unsigned short u) {
  union { unsigned int i; float f; } v; v.i = ((unsigned int)u) << 16; return v.f;
}
// async global->LDS, 16B per lane; LDS dest must be wave-uniform base + lane*16
__device__ __forceinline__ void gl_lds16(const unsigned short* g, unsigned short* l) {
  __builtin_amdgcn_global_load_lds(
      (const __attribute__((address_space(1))) unsigned int*)g,
      (__attribute__((address_space(3))) unsigned int*)l, 16, 0, 0);
}

// ---------------------------------------------------------------------------
// cvt: f32 -> bf16 rowmajor copy (source -> SB)
// ---------------------------------------------------------------------------
__global__ __launch_bounds__(256) void cvt_bf16_kernel(const float* __restrict__ src,
                                                       unsigned short* __restrict__ dst) {
  int i = (blockIdx.x * 256 + threadIdx.x) * 4;
  float4 v = *(const float4*)&src[i];
  ushort4 o = make_ushort4(f2bf(v.x), f2bf(v.y), f2bf(v.z), f2bf(v.w));
  *(ushort4*)&dst[i] = o;
}

// ---------------------------------------------------------------------------
// Fused small preps (validated round 12): [0,256) T(Wf1); [256,384) T(Wf2);
// [384,400) precM; [400,408) precWVM.
// ---------------------------------------------------------------------------
__global__ __launch_bounds__(256) void prep_small_kernel(
    const float* __restrict__ Wf1, const float* __restrict__ Wf2,
    const float* __restrict__ Wq, const float* __restrict__ Wk,
    const float* __restrict__ Wv, const float* __restrict__ Wm,
    unsigned short* __restrict__ WF1t, unsigned short* __restrict__ WF2t,
    unsigned short* __restrict__ Mt, unsigned short* __restrict__ WVMt) {
  __shared__ __align__(16) char smem[66688];
  const int b = blockIdx.x;
  const int tid = threadIdx.x;

  if (b < 384) {
    const float* src; unsigned short* dst; int K, N, k0, n0;
    if (b < 256) { src = Wf1; dst = WF1t; K = 512;  N = 2048; k0 = (b & 7) * 64;  n0 = (b >> 3) * 64; }
    else { int bb = b - 256; src = Wf2; dst = WF2t; K = 2048; N = 256;  k0 = (bb & 31) * 64; n0 = (bb >> 5) * 64; }
    float (*tile)[65] = (float (*)[65])smem;
#pragma unroll
    for (int i = 0; i < 16; i++) {
      int lin = i * 256 + tid, r = lin >> 6, c = lin & 63;
      tile[r][c] = src[(size_t)(k0 + r) * N + n0 + c];
    }
    __syncthreads();
#pragma unroll
    for (int i = 0; i < 16; i++) {
      int lin = i * 256 + tid, n = lin >> 6, k = lin & 63;
      dst[(size_t)(n0 + n) * K + k0 + k] = f2bf(tile[k][n]);
    }
  } else if (b < 400) {
    const int hb = b - 384;
    const int h = hb >> 1, eh = hb & 1;
    float (*wqS)[33] = (float (*)[33])smem;
    float (*wkS)[33] = (float (*)[33])(smem + 256 * 33 * 4);
#pragma unroll
    for (int it = 0; it < 32; it++) {
      int lin = it * 256 + tid, r = lin >> 5, d = lin & 31;
      wqS[r][d] = Wq[(size_t)r * CC + h * DD + d];
    }
#pragma unroll
    for (int it = 0; it < 16; it++) {
      int lin = it * 256 + tid, r = lin >> 5, d = lin & 31;
      wkS[r][d] = Wk[(size_t)(eh * 128 + r) * CC + h * DD + d];
    }
    __syncthreads();
    const int w = tid >> 6, l = tid & 63;
    for (int ei = 0; ei < 32; ei++) {
      int e = w * 32 + ei;
      float o[4] = {0.f, 0.f, 0.f, 0.f};
#pragma unroll
      for (int d = 0; d < 32; d++) {
        float kv = wkS[e][d];
        o[0] += kv * wqS[l][d];
        o[1] += kv * wqS[l + 64][d];
        o[2] += kv * wqS[l + 128][d];
        o[3] += kv * wqS[l + 192][d];
      }
      size_t rowb = (size_t)(h * 256 + eh * 128 + e) * CC;
      Mt[rowb + l] = f2bf(o[0]);
      Mt[rowb + l + 64] = f2bf(o[1]);
      Mt[rowb + l + 128] = f2bf(o[2]);
      Mt[rowb + l + 192] = f2bf(o[3]);
    }
  } else {
    const int h = b - 400;
    float (*WvS)[33] = (float (*)[33])smem;
    float (*WmS)[257] = (float (*)[257])(smem + 256 * 33 * 4);
#pragma unroll
    for (int it = 0; it < 32; it++) {
      int lin = it * 256 + tid, e = lin >> 5, d = lin & 31;
      WvS[e][d] = Wv[(size_t)e * CC + h * DD + d];
    }
#pragma unroll
    for (int it = 0; it < 32; it++) {
      int lin = it * 256 + tid, d = lin >> 8, c = lin & 255;
      WmS[d][c] = Wm[(size_t)(h * DD + d) * CC + c];
    }
    __syncthreads();
    float wm[32];
#pragma unroll
    for (int d = 0; d < 32; d++) wm[d] = WmS[d][tid];
    for (int e = 0; e < 256; e++) {
      float acc = 0.f;
#pragma unroll
      for (int d = 0; d < 32; d++) acc += WvS[e][d] * wm[d];
      WVMt[(size_t)tid * 2048 + h * 256 + e] = f2bf(acc);
    }
  }
}

// ---------------------------------------------------------------------------
// QK GEMM: Out = A[M,256] @ Bt^T. BM=128, BN=256, BK=64, 512 thr, 8 waves
// (2x4), wave tile 64x64 — clone of the validated gemm1 structure (r13),
// minus concat and gelu. 32 MFMA per barrier pair; 48 KB LDS (3 blocks/CU).
// ---------------------------------------------------------------------------
__global__ __launch_bounds__(512) void qk_gemm_kernel(
    const unsigned short* __restrict__ A, const unsigned short* __restrict__ Bt,
    unsigned short* __restrict__ Out, int K, int strideO) {
  __shared__ __align__(16) unsigned short As[128 * 64];   // 16 KB
  __shared__ __align__(16) unsigned short Bs[256 * 64];   // 32 KB
  const int tid = threadIdx.x;
  const int wv = tid >> 6, l = tid & 63;
  const int wr = wv >> 2, wc = wv & 3;
  const int lr = l & 15, lq = l >> 4;
  const int m0 = blockIdx.x * 128;
  const int n0 = blockIdx.y * 256;
  const int nsteps = K >> 6;

  f32x4_t acc[4][4];
#pragma unroll
  for (int m = 0; m < 4; m++)
#pragma unroll
    for (int n = 0; n < 4; n++) acc[m][n] = (f32x4_t){0.f, 0.f, 0.f, 0.f};

  for (int st = 0; st < nsteps; st++) {
    int kn = st * 64;
    // A: 128 rows x 64 k = 1024 x 16B chunks, 2 per thread
#pragma unroll
    for (int it = 0; it < 2; it++) {
      int lin = it * 512 + tid, r = lin >> 3, s = lin & 7, q = s ^ (r & 7);
      gl_lds16(&A[(size_t)(m0 + r) * K + kn + q * 8], &As[lin * 8]);
    }
    // B: 256 rows x 64 k = 2048 chunks, 4 per thread
#pragma unroll
    for (int it = 0; it < 4; it++) {
      int lin = it * 512 + tid, r = lin >> 3, s = lin & 7, q = s ^ (r & 7);
      gl_lds16(&Bt[(size_t)(n0 + r) * K + kn + q * 8], &Bs[lin * 8]);
    }
    __syncthreads();
#pragma unroll
    for (int kk = 0; kk < 2; kk++) {
      bf16x8_t af[4], bfr[4];
#pragma unroll
      for (int m = 0; m < 4; m++) {
        int r = wr * 64 + m * 16 + lr;
        int slot = (kk * 4 + lq) ^ (r & 7);
        af[m] = *(const bf16x8_t*)&As[r * 64 + slot * 8];
      }
#pragma unroll
      for (int n = 0; n < 4; n++) {
        int r = wc * 64 + n * 16 + lr;
        int slot = (kk * 4 + lq) ^ (r & 7);
        bfr[n] = *(const bf16x8_t*)&Bs[r * 64 + slot * 8];
      }
#pragma unroll
      for (int m = 0; m < 4; m++)
#pragma unroll
        for (int n = 0; n < 4; n++)
          acc[m][n] = __builtin_amdgcn_mfma_f32_16x16x32_bf16(af[m], bfr[n], acc[m][n], 0, 0, 0);
    }
    __syncthreads();
  }

#pragma unroll
  for (int m = 0; m < 4; m++)
#pragma unroll
    for (int n = 0; n < 4; n++)
#pragma unroll
      for (int j = 0; j < 4; j++) {
        int row = m0 + wr * 64 + m * 16 + lq * 4 + j;
        int col = n0 + wc * 64 + n * 16 + lr;
        Out[(size_t)row * strideO + col] = f2bf(acc[m][n][j]);
      }
}

// ---------------------------------------------------------------------------
// gemm1: hid = gelu([A||A2][M,512] @ Bt^T). BM=128, BN=256, BK=64, 512 thr
// (validated round 13).
// ---------------------------------------------------------------------------
__global__ __launch_bounds__(512) void gemm1_kernel(
    const unsigned short* __restrict__ A, const unsigned short* __restrict__ A2,
    const unsigned short* __restrict__ Bt, unsigned short* __restrict__ Out,
    int K, int strideO) {
  __shared__ __align__(16) unsigned short As[128 * 64];   // 16 KB
  __shared__ __align__(16) unsigned short Bs[256 * 64];   // 32 KB
  const int tid = threadIdx.x;
  const int wv = tid >> 6, l = tid & 63;
  const int wr = wv >> 2, wc = wv & 3;
  const int lr = l & 15, lq = l >> 4;
  const int m0 = blockIdx.x * 128;
  const int n0 = blockIdx.y * 256;
  const int nsteps = K >> 6;

  f32x4_t acc[4][4];
#pragma unroll
  for (int m = 0; m < 4; m++)
#pragma unroll
    for (int n = 0; n < 4; n++) acc[m][n] = (f32x4_t){0.f, 0.f, 0.f, 0.f};

  for (int st = 0; st < nsteps; st++) {
    int kn = st * 64;
#pragma unroll
    for (int it = 0; it < 2; it++) {
      int lin = it * 512 + tid, r = lin >> 3, s = lin & 7, q = s ^ (r & 7);
      int ka = kn + q * 8;
      const unsigned short* ap = (ka < 256) ? &A[(size_t)(m0 + r) * CC + ka]
                                            : &A2[(size_t)(m0 + r) * CC + ka - 256];
      gl_lds16(ap, &As[lin * 8]);
    }
#pragma unroll
    for (int it = 0; it < 4; it++) {
      int lin = it * 512 + tid, r = lin >> 3, s = lin & 7, q = s ^ (r & 7);
      gl_lds16(&Bt[(size_t)(n0 + r) * K + kn + q * 8], &Bs[lin * 8]);
    }
    __syncthreads();
#pragma unroll
    for (int kk = 0; kk < 2; kk++) {
      bf16x8_t af[4], bf[4];
#pragma unroll
      for (int m = 0; m < 4; m++) {
        int r = wr * 64 + m * 16 + lr;
        int slot = (kk * 4 + lq) ^ (r & 7);
        af[m] = *(const bf16x8_t*)&As[r * 64 + slot * 8];
      }
#pragma unroll
      for (int n = 0; n < 4; n++) {
        int r = wc * 64 + n * 16 + lr;
        int slot = (kk * 4 + lq) ^ (r & 7);
        bf[n] = *(const bf16x8_t*)&Bs[r * 64 + slot * 8];
      }
#pragma unroll
      for (int m = 0; m < 4; m++)
#pragma unroll
        for (int n = 0; n < 4; n++)
          acc[m][n] = __builtin_amdgcn_mfma_f32_16x16x32_bf16(af[m], bf[n], acc[m][n], 0, 0, 0);
    }
    __syncthreads();
  }

#pragma unroll
  for (int m = 0; m < 4; m++)
#pragma unroll
    for (int n = 0; n < 4; n++)
#pragma unroll
      for (int j = 0; j < 4; j++) {
        int row = m0 + wr * 64 + m * 16 + lq * 4 + j;
        int col = n0 + wc * 64 + n * 16 + lr;
        float x = acc[m][n][j];
        x = 0.5f * x * (1.0f + erff(x * 0.70710678118654752f));
        Out[(size_t)row * strideO + col] = f2bf(x);
      }
}

// ---------------------------------------------------------------------------
// attn2: per wave = one token (unchanged; validated rounds 6-13).
// ---------------------------------------------------------------------------
__global__ __launch_bounds__(256) void attn2_kernel(const unsigned short* __restrict__ QKc,
                                                    const float* __restrict__ target,
                                                    const float* __restrict__ wts,
                                                    const float* __restrict__ conf,
                                                    unsigned short* __restrict__ TC) {
  __shared__ __align__(16) unsigned short Ts[4][16 * 256];
  __shared__ float awL[4][PP][HH];
  const int tid = threadIdx.x;
  const int w = tid >> 6, l = tid & 63;
  const int t = blockIdx.x * 4 + w;
  const float* trow = target + (size_t)t * PP * CC;
  char* tsb = (char*)&Ts[w][0];

  {
    const int p = l >> 2;
#pragma unroll
    for (int i = 0; i < 8; i++) {
      int s = (l & 3) + i * 4;
      const float* gp = &trow[p * CC + s * 8];
      float4 v0 = *(const float4*)gp;
      float4 v1 = *(const float4*)(gp + 4);
      ushort4 u0 = make_ushort4(f2bf(v0.x), f2bf(v0.y), f2bf(v0.z), f2bf(v0.w));
      ushort4 u1 = make_ushort4(f2bf(v1.x), f2bf(v1.y), f2bf(v1.z), f2bf(v1.w));
      uint4 pk;
      pk.x = (unsigned)u0.x | ((unsigned)u0.y << 16);
      pk.y = (unsigned)u0.z | ((unsigned)u0.w << 16);
      pk.z = (unsigned)u1.x | ((unsigned)u1.y << 16);
      pk.w = (unsigned)u1.z | ((unsigned)u1.w << 16);
      *(uint4*)(tsb + p * 512 + ((s ^ (p & 7)) << 4)) = pk;
    }
  }

  f32x4_t sc4 = (f32x4_t){0.f, 0.f, 0.f, 0.f};
  {
    const int lr = l & 15, lq = l >> 4;
    const unsigned short* qkrow = QKc + (size_t)t * 2048 + (size_t)(lr & 7) * 256;
#pragma unroll
    for (int es = 0; es < 8; es++) {
      int slot = es * 4 + lq;
      bf16x8_t aF = *(const bf16x8_t*)(tsb + lr * 512 + ((slot ^ (lr & 7)) << 4));
      bf16x8_t bF = *(const bf16x8_t*)&qkrow[es * 32 + lq * 8];
      sc4 = __builtin_amdgcn_mfma_f32_16x16x32_bf16(aF, bF, sc4, 0, 0, 0);
    }
  }

  {
    const int g = l >> 4;
    const float rsD = 0.17677669529663687f;
    float sc[4], cf[4];
#pragma unroll
    for (int j = 0; j < 4; j++) {
      int p = g * 4 + j;
      sc[j] = sc4[j] * wts[(size_t)t * PP + p] * rsD;
      cf[j] = conf[(size_t)t * PP + p];
    }
    float mx = fmaxf(fmaxf(sc[0], sc[1]), fmaxf(sc[2], sc[3]));
    mx = fmaxf(mx, __shfl_xor(mx, 16, 64));
    mx = fmaxf(mx, __shfl_xor(mx, 32, 64));
    float ex[4], sm = 0.f;
#pragma unroll
    for (int j = 0; j < 4; j++) { ex[j] = expf(sc[j] - mx); sm += ex[j]; }
    sm += __shfl_xor(sm, 16, 64);
    sm += __shfl_xor(sm, 32, 64);
    float inv = 1.f / sm;
    if ((l & 15) < 8) {
#pragma unroll
      for (int j = 0; j < 4; j++) awL[w][g * 4 + j][l & 15] = ex[j] * inv * cf[j];
    }
  }

  float tc[HH][4];
#pragma unroll
  for (int h = 0; h < HH; h++)
#pragma unroll
    for (int j = 0; j < 4; j++) tc[h][j] = 0.f;
#pragma unroll
  for (int p = 0; p < PP; p++) {
    uint2 tv = *(const uint2*)(tsb + p * 512 + (((l >> 1) ^ (p & 7)) << 4) + (l & 1) * 8);
    float te0 = bf2f((unsigned short)(tv.x & 0xffff));
    float te1 = bf2f((unsigned short)(tv.x >> 16));
    float te2 = bf2f((unsigned short)(tv.y & 0xffff));
    float te3 = bf2f((unsigned short)(tv.y >> 16));
#pragma unroll
    for (int h = 0; h < HH; h++) {
      float a = awL[w][p][h];
      tc[h][0] += a * te0; tc[h][1] += a * te1;
      tc[h][2] += a * te2; tc[h][3] += a * te3;
    }
  }
  size_t tcb = (size_t)t * 2048;
#pragma unroll
  for (int h = 0; h < HH; h++) {
    ushort4 o = make_ushort4(f2bf(tc[h][0]), f2bf(tc[h][1]), f2bf(tc[h][2]), f2bf(tc[h][3]));
    *(ushort4*)&TC[tcb + h * 256 + 4 * l] = o;
  }
}

// ---------------------------------------------------------------------------
// nwide GEMM (BM=32, BN=256, K=2048), BK=128 single-buffer (validated r12).
// EPI: 0 = LN -> bf16; 1 = LN + residual -> f32.
// ---------------------------------------------------------------------------
template<int EPI>
__global__ __launch_bounds__(256) void nwide_gemm_kernel(
    const unsigned short* __restrict__ A, const unsigned short* __restrict__ Bt,
    unsigned short* __restrict__ OutB, float* __restrict__ OutF,
    const float* __restrict__ gam, const float* __restrict__ bet,
    const float* __restrict__ res) {
  __shared__ __align__(16) unsigned short As[32 * 128];    // 8 KB
  __shared__ __align__(16) unsigned short Bs[256 * 128];   // 64 KB
  __shared__ float redS[32][5], redQ[32][5];
  const int tid = threadIdx.x;
  const int wc = tid >> 6, l = tid & 63;
  const int lr = l & 15, lq = l >> 4;
  const int m0 = blockIdx.x * 32;
  const int K = 2048;

  f32x4_t acc[2][4];
#pragma unroll
  for (int m = 0; m < 2; m++)
#pragma unroll
    for (int n = 0; n < 4; n++) acc[m][n] = (f32x4_t){0.f, 0.f, 0.f, 0.f};

  for (int st = 0; st < 16; st++) {
    int kn = st * 128;
#pragma unroll
    for (int it = 0; it < 2; it++) {
      int lin = it * 256 + tid, r = lin >> 4, s = lin & 15, q = s ^ (r & 15);
      gl_lds16(&A[(size_t)(m0 + r) * K + kn + q * 8], &As[lin * 8]);
    }
#pragma unroll
    for (int it = 0; it < 16; it++) {
      int lin = it * 256 + tid, r = lin >> 4, s = lin & 15, q = s ^ (r & 15);
      gl_lds16(&Bt[(size_t)r * K + kn + q * 8], &Bs[lin * 8]);
    }
    __syncthreads();
#pragma unroll
    for (int kk = 0; kk < 4; kk++) {
      bf16x8_t af[2], bfr[4];
#pragma unroll
      for (int m = 0; m < 2; m++) {
        int r = m * 16 + lr;
        int slot = (kk * 4 + lq) ^ (r & 15);
        af[m] = *(const bf16x8_t*)&As[r * 128 + slot * 8];
      }
#pragma unroll
      for (int n = 0; n < 4; n++) {
        int r = wc * 64 + n * 16 + lr;
        int slot = (kk * 4 + lq) ^ (r & 15);
        bfr[n] = *(const bf16x8_t*)&Bs[r * 128 + slot * 8];
      }
#pragma unroll
      for (int m = 0; m < 2; m++)
#pragma unroll
        for (int n = 0; n < 4; n++)
          acc[m][n] = __builtin_amdgcn_mfma_f32_16x16x32_bf16(af[m], bfr[n], acc[m][n], 0, 0, 0);
    }
    __syncthreads();
  }

  // LN epilogue (block covers the full 256-col row)
  float s1[2][4], s2[2][4];
#pragma unroll
  for (int m = 0; m < 2; m++)
#pragma unroll
    for (int j = 0; j < 4; j++) {
      float a = 0.f, b = 0.f;
#pragma unroll
      for (int n = 0; n < 4; n++) { float x = acc[m][n][j]; a += x; b += x * x; }
      s1[m][j] = a; s2[m][j] = b;
    }
#pragma unroll
  for (int mask = 1; mask < 16; mask <<= 1)
#pragma unroll
    for (int m = 0; m < 2; m++)
#pragma unroll
      for (int j = 0; j < 4; j++) {
        s1[m][j] += __shfl_xor(s1[m][j], mask, 64);
        s2[m][j] += __shfl_xor(s2[m][j], mask, 64);
      }
  if (lr == 0) {
#pragma unroll
    for (int m = 0; m < 2; m++)
#pragma unroll
      for (int j = 0; j < 4; j++) {
        int rl = m * 16 + lq * 4 + j;
        redS[rl][wc] = s1[m][j];
        redQ[rl][wc] = s2[m][j];
      }
  }
  __syncthreads();
#pragma unroll
  for (int m = 0; m < 2; m++)
#pragma unroll
    for (int j = 0; j < 4; j++) {
      int rl = m * 16 + lq * 4 + j;
      float ts = redS[rl][0] + redS[rl][1] + redS[rl][2] + redS[rl][3];
      float tq = redQ[rl][0] + redQ[rl][1] + redQ[rl][2] + redQ[rl][3];
      float mu = ts * (1.f / 256.f);
      float var = tq * (1.f / 256.f) - mu * mu;
      float rs = rsqrtf(var + LN_EPS);
      size_t rowg = (size_t)(m0 + rl);
#pragma unroll
      for (int n = 0; n < 4; n++) {
        int col = wc * 64 + n * 16 + lr;
        float v = (acc[m][n][j] - mu) * rs * gam[col] + bet[col];
        if constexpr (EPI == 0) {
          OutB[rowg * CC + col] = f2bf(v);
        } else {
          OutF[rowg * CC + col] = res[rowg * CC + col] + v;
        }
      }
    }
}

extern "C" void kernel_launch(void* const* d_in, const int* in_sizes, int n_in,
                              void* d_out, int out_size, void* d_ws, size_t ws_size,
                              hipStream_t stream) {
  const float* source = (const float*)d_in[0];
  const float* target = (const float*)d_in[1];
  const float* weights = (const float*)d_in[2];
  const float* conf   = (const float*)d_in[3];
  const float* Wq = (const float*)d_in[4];
  const float* Wk = (const float*)d_in[5];
  const float* Wv = (const float*)d_in[6];
  const float* Wm = (const float*)d_in[7];
  const float* g1 = (const float*)d_in[8];
  const float* b1 = (const float*)d_in[9];
  const float* Wf1 = (const float*)d_in[10];
  const float* Wf2 = (const float*)d_in[11];
  const float* g2 = (const float*)d_in[12];
  const float* b2 = (const float*)d_in[13];
  float* out = (float*)d_out;

  unsigned short* SB   = (unsigned short*)d_ws;                 // [16384][256]
  unsigned short* MSGb = SB + (size_t)T_TOK * CC;               // [16384][256]
  unsigned short* Mt   = MSGb + (size_t)T_TOK * CC;             // [2048][256]
  unsigned short* WVMt = Mt + (size_t)2048 * 256;               // [256][2048]
  unsigned short* WF1t = WVMt + (size_t)256 * 2048;             // [2048][512]
  unsigned short* WF2t = WF1t + (size_t)2048 * 512;             // [256][2048]
  unsigned short* BIG1 = WF2t + (size_t)256 * 2048;             // QKc, later hid
  unsigned short* BIG2 = BIG1 + (size_t)T_TOK * 2048;           // TC
  unsigned short* QKc  = BIG1;
  unsigned short* hid  = BIG1;
  unsigned short* TC   = BIG2;

  // prep
  cvt_bf16_kernel<<<T_TOK * CC / 1024, 256, 0, stream>>>(source, SB);
  prep_small_kernel<<<408, 256, 0, stream>>>(Wf1, Wf2, Wq, Wk, Wv, Wm,
                                             WF1t, WF2t, Mt, WVMt);

  // attention pipeline: QKc = SB @ Mt^T  (128x256 tiles)
  qk_gemm_kernel<<<dim3(T_TOK / 128, 8), 512, 0, stream>>>(SB, Mt, QKc, 256, 2048);
  attn2_kernel<<<T_TOK / 4, 256, 0, stream>>>(QKc, target, weights, conf, TC);
  // message = LN(TC @ WVMt^T)
  nwide_gemm_kernel<0><<<T_TOK / 32, 256, 0, stream>>>(
      TC, WVMt, MSGb, nullptr, g1, b1, nullptr);

  // FFN: hid = gelu([SB||MSG] @ W1t^T)  (128x256 tiles)
  gemm1_kernel<<<dim3(T_TOK / 128, 8), 512, 0, stream>>>(
      SB, MSGb, WF1t, hid, 512, 2048);
  // out = src + LN(hid @ W2t^T)
  nwide_gemm_kernel<1><<<T_TOK / 32, 256, 0, stream>>>(
      hid, WF2t, nullptr, out, g2, b2, source);
}